// Round 13
// baseline (778.011 us; speedup 1.0000x reference)
//
#include <hip/hip_runtime.h>
#include <math.h>

// Problem constants (fixed by the reference)
#define BN   8
#define NN   1024
#define FIN  256
#define HIDN 128
#define KTOP 513          // int(1024*0.5)+1
#define NITER 20          // opt_epochs in setup_inputs
#define EPS_S 0.01f
#define INV_EPS 100.0f
#define LOG_MU (-6.9314718055994531f)   // -log(1024)
#define SNB 256           // blocks in persistent sinkhorn kernel
#define SENTU 0xFFFFFFFFu

typedef __attribute__((ext_vector_type(8))) short bfrag8;   // 8 bf16 (4 VGPR)
typedef __attribute__((ext_vector_type(4))) float facc4;    // MFMA accumulator

#define GLOAD16(g, l) __builtin_amdgcn_global_load_lds( \
    (const __attribute__((address_space(1))) unsigned int*)(g), \
    (__attribute__((address_space(3))) unsigned int*)(l), 16, 0, 0)

static __device__ __forceinline__ float wred_sum(float s) {
#pragma unroll
  for (int o = 32; o > 0; o >>= 1) s += __shfl_xor(s, o);
  return s;
}
static __device__ __forceinline__ unsigned short f2b(float f) {
  unsigned int u = __float_as_uint(f);
  u += 0x7fff + ((u >> 16) & 1);      // RNE
  return (unsigned short)(u >> 16);
}
static __device__ __forceinline__ float b2f(unsigned short h) {
  return __uint_as_float((unsigned int)h << 16);
}

// ---- rowstats (4 rows/block) from fp32: d, rmask; optional bf16+fp32 copy --
template<int WRBF, int WCOPY>
__global__ __launch_bounds__(256) void k_rowstats4(const float* __restrict__ adj,
                                                   float* __restrict__ dv,
                                                   float* __restrict__ rm,
                                                   unsigned short* __restrict__ abf,
                                                   float* __restrict__ ocopy) {
  int r0 = blockIdx.x << 2;
  int t = threadIdx.x, lane = t & 63, wv = t >> 6;
  __shared__ float sm[4][4];
#pragma unroll
  for (int r = 0; r < 4; ++r) {
    float4 v = ((const float4*)(adj + (long)(r0 + r) * NN))[t];
    if (WRBF) {
      ushort4 h; h.x = f2b(v.x); h.y = f2b(v.y); h.z = f2b(v.z); h.w = f2b(v.w);
      *(ushort4*)(abf + (long)(r0 + r) * NN + t * 4) = h;
    }
    if (WCOPY) ((float4*)(ocopy + (long)(r0 + r) * NN))[t] = v;
    float s = (v.x + v.y) + (v.z + v.w);
    s = wred_sum(s);
    if (lane == 0) sm[wv][r] = s;
  }
  __syncthreads();
  if (t < 4) {
    float tot = sm[0][t] + sm[1][t] + sm[2][t] + sm[3][t];
    dv[r0 + t] = rsqrtf(fmaxf(tot + 1.0f, 1.0f));
    rm[r0 + t] = tot > 0.0f ? 1.0f : 0.0f;
  }
}

// ---- d/rm from fused rowsum buffer -----------------------------------------
__global__ __launch_bounds__(256) void k_dfrom(const float* __restrict__ rs,
                                               float* __restrict__ dv,
                                               float* __restrict__ rm) {
  int i = blockIdx.x * 256 + threadIdx.x;
  float tot = rs[i];
  dv[i] = rsqrtf(fmaxf(tot + 1.0f, 1.0f));
  rm[i] = tot > 0.0f ? 1.0f : 0.0f;
}

// ---------------- fp32 -> bf16 elementwise ----------------------------------
__global__ __launch_bounds__(256) void k_f2b(const float* __restrict__ X,
                                             unsigned short* __restrict__ Y) {
  long i = ((long)blockIdx.x * 256 + threadIdx.x) * 4;
  float4 v = *(const float4*)(X + i);
  Y[i] = f2b(v.x); Y[i + 1] = f2b(v.y); Y[i + 2] = f2b(v.z); Y[i + 3] = f2b(v.w);
}

// ---- W1 [256][128] fp32 -> W1t [128][256] bf16 -----------------------------
__global__ __launch_bounds__(256) void k_w1t(const float* __restrict__ W,
                                             unsigned short* __restrict__ Wt) {
  int idx = blockIdx.x * 256 + threadIdx.x;   // 32768
  int n = idx >> 8, k = idx & 255;
  Wt[idx] = f2b(W[k * HIDN + n]);
}

// ---- fused sqnorm + hi/lo bf16 split for BOTH x and x2 (grid 4096) ---------
__global__ __launch_bounds__(256) void k_prep2(
    const float* __restrict__ X0, const float* __restrict__ X1,
    unsigned short* __restrict__ Xh0, unsigned short* __restrict__ Xl0,
    unsigned short* __restrict__ Xh1, unsigned short* __restrict__ Xl1,
    float* __restrict__ sq0, float* __restrict__ sq1) {
  int bb = blockIdx.x;
  const float* X; unsigned short* Xh; unsigned short* Xl; float* sq; int rb;
  if (bb < 2048) { X = X0; Xh = Xh0; Xl = Xl0; sq = sq0; rb = bb; }
  else { X = X1; Xh = Xh1; Xl = Xl1; sq = sq1; rb = bb - 2048; }
  int t = threadIdx.x, lane = t & 63, wv = t >> 6;
  int row = rb * 4 + wv;
  long base = (long)row * FIN + lane * 4;
  float4 v = *(const float4*)(X + base);
  ushort4 h, l;
  h.x = f2b(v.x); l.x = f2b(v.x - b2f(h.x));
  h.y = f2b(v.y); l.y = f2b(v.y - b2f(h.y));
  h.z = f2b(v.z); l.z = f2b(v.z - b2f(h.z));
  h.w = f2b(v.w); l.w = f2b(v.w - b2f(h.w));
  *(ushort4*)(Xh + base) = h;
  *(ushort4*)(Xl + base) = l;
  float s = v.x * v.x + v.y * v.y + v.z * v.z + v.w * v.w;
  s = wred_sum(s);
  if (lane == 0) sq[row] = s;
}

// ---------------- fp32 [R][C] -> bf16 [C][R] transpose ----------------------
__global__ __launch_bounds__(256) void k_transp(const float* __restrict__ X,
                                                unsigned short* __restrict__ Xt,
                                                int R, int C) {
  __shared__ float tile[64][65];
  long bb = blockIdx.z;
  const float* Xb = X + bb * (long)R * C;
  unsigned short* Xtb = Xt + bb * (long)R * C;
  int r0 = blockIdx.y * 64, c0 = blockIdx.x * 64;
  int t = threadIdx.x;
  int tr = t >> 4, tc4 = (t & 15) * 4;
#pragma unroll
  for (int p = 0; p < 4; ++p) {
    float4 v = *(const float4*)(Xb + (long)(r0 + tr + p * 16) * C + c0 + tc4);
    tile[tr + p * 16][tc4 + 0] = v.x; tile[tr + p * 16][tc4 + 1] = v.y;
    tile[tr + p * 16][tc4 + 2] = v.z; tile[tr + p * 16][tc4 + 3] = v.w;
  }
  __syncthreads();
  int jj = t >> 2, i0 = (t & 3) * 16;
  unsigned short* orow = Xtb + (long)(c0 + jj) * R + r0 + i0;
#pragma unroll
  for (int q = 0; q < 16; ++q) orow[q] = f2b(tile[i0 + q][jj]);
}

// ---- scale-transpose-cast: Bg[b][n][j] = bf16(d[b*1024+j]*XW[b][j][n]) -----
template<int SPLIT>
__global__ __launch_bounds__(256) void k_stc(const float* __restrict__ XW,
                                             const float* __restrict__ dvv,
                                             unsigned short* __restrict__ Bh,
                                             unsigned short* __restrict__ Bl,
                                             int F) {
  __shared__ float tile[64][65];
  __shared__ float dl[64];
  int bz = blockIdx.z;
  const float* Xb = XW + (long)bz * NN * F;
  int j0 = blockIdx.x * 64;   // node dim
  int n0 = blockIdx.y * 64;   // feature dim
  int t = threadIdx.x;
  int tr = t >> 4, tc4 = (t & 15) * 4;
#pragma unroll
  for (int p = 0; p < 4; ++p) {
    float4 v = *(const float4*)(Xb + (long)(j0 + tr + p * 16) * F + n0 + tc4);
    tile[tr + p * 16][tc4 + 0] = v.x; tile[tr + p * 16][tc4 + 1] = v.y;
    tile[tr + p * 16][tc4 + 2] = v.z; tile[tr + p * 16][tc4 + 3] = v.w;
  }
  if (t < 64) dl[t] = dvv[(bz << 10) + j0 + t];
  __syncthreads();
  int nn = t >> 2, i0 = (t & 3) * 16;
  long obase = ((long)bz * F + n0 + nn) * NN + j0 + i0;
#pragma unroll
  for (int q = 0; q < 16; ++q) {
    float v = tile[i0 + q][nn] * dl[i0 + q];
    unsigned short h = f2b(v);
    Bh[obase + q] = h;
    if (SPLIT) Bl[obase + q] = f2b(v - b2f(h));
  }
}

// ---------------- bf16 NT MFMA GEMM: C[m,n] = sum_k A[m,k]*B[n,k] -----------
// WBF: 0 none, 1 bf16, 2 bf16 hi+lo; RS: accumulate fp32 row sums into RSp
template<int WF32, int WBF, int RS>
__global__ __launch_bounds__(256) void k_mfma_nt(
    const unsigned short* __restrict__ A, const unsigned short* __restrict__ B,
    float* __restrict__ Cf, unsigned short* __restrict__ Cb,
    unsigned short* __restrict__ Cb2,
    int K, int ldA, int ldB, int ldC, long sA, long sB, long sC,
    float* __restrict__ RSp) {
  __shared__ unsigned short As[128 * 32];
  __shared__ unsigned short Bs[128 * 32];
  __shared__ float rsum[RS ? 128 : 4];
  int bz = blockIdx.z;
  A += bz * sA; B += bz * sB;
  int m0 = blockIdx.y * 128, n0 = blockIdx.x * 128;
  int tid = threadIdx.x, lane = tid & 63, w = tid >> 6;
  int wr = w >> 1, wc = w & 1;
  facc4 acc[4][4];
#pragma unroll
  for (int i = 0; i < 4; ++i)
#pragma unroll
    for (int j = 0; j < 4; ++j)
#pragma unroll
      for (int q = 0; q < 4; ++q) acc[i][j][q] = 0.f;

  int rA0 = w * 16 + (lane >> 2);
  int kslot = lane & 3;

  for (int k0 = 0; k0 < K; k0 += 32) {
#pragma unroll
    for (int i = 0; i < 2; ++i) {
      int row = i * 64 + rA0;
      int ks = (kslot ^ (row & 3)) << 3;   // pre-swizzled global source
      GLOAD16(A + (long)(m0 + row) * ldA + k0 + ks, As + (i * 64 + w * 16) * 32);
      GLOAD16(B + (long)(n0 + row) * ldB + k0 + ks, Bs + (i * 64 + w * 16) * 32);
    }
    __syncthreads();
    bfrag8 af[4], bfr[4];
#pragma unroll
    for (int mi = 0; mi < 4; ++mi) {
      int row = wr * 64 + mi * 16 + (lane & 15);
      int sl = (((lane >> 4) ^ (row & 3)) << 3);   // swizzled read
      af[mi] = *(const bfrag8*)(As + row * 32 + sl);
    }
#pragma unroll
    for (int ni = 0; ni < 4; ++ni) {
      int row = wc * 64 + ni * 16 + (lane & 15);
      int sl = (((lane >> 4) ^ (row & 3)) << 3);
      bfr[ni] = *(const bfrag8*)(Bs + row * 32 + sl);
    }
#pragma unroll
    for (int mi = 0; mi < 4; ++mi)
#pragma unroll
      for (int ni = 0; ni < 4; ++ni)
        acc[mi][ni] = __builtin_amdgcn_mfma_f32_16x16x32_bf16(
            af[mi], bfr[ni], acc[mi][ni], 0, 0, 0);
    __syncthreads();
  }
  if (RS) {
    if (tid < 128) rsum[tid] = 0.f;
    __syncthreads();
  }
  if (WF32) Cf += bz * sC;
  if (WBF) Cb += bz * sC;
  if (WBF == 2) Cb2 += bz * sC;
#pragma unroll
  for (int mi = 0; mi < 4; ++mi) {
    int rowb = m0 + wr * 64 + mi * 16 + ((lane >> 4) << 2);
#pragma unroll
    for (int q = 0; q < 4; ++q) {
      float rp = 0.f;
#pragma unroll
      for (int ni = 0; ni < 4; ++ni) {
        int col = n0 + wc * 64 + ni * 16 + (lane & 15);
        long off = (long)(rowb + q) * ldC + col;
        float v = acc[mi][ni][q];
        if (WF32) Cf[off] = v;
        if (WBF == 1) Cb[off] = f2b(v);
        if (WBF == 2) {
          unsigned short h = f2b(v);
          Cb[off] = h;
          Cb2[off] = f2b(v - b2f(h));
        }
        if (RS) rp += v;
      }
      if (RS) {
        rp += __shfl_xor(rp, 1); rp += __shfl_xor(rp, 2);
        rp += __shfl_xor(rp, 4); rp += __shfl_xor(rp, 8);
        if ((lane & 15) == 0)
          atomicAdd(&rsum[rowb + q - m0], rp);
      }
    }
  }
  if (RS) {
    __syncthreads();
    if (tid < 128) atomicAdd(&RSp[(long)bz * NN + m0 + tid], rsum[tid]);
  }
}

// ---- merged coarsening GEMM: grid (9, 8, 8) --------------------------------
__global__ __launch_bounds__(256) void k_coars(
    const unsigned short* __restrict__ St, const unsigned short* __restrict__ Badj,
    const unsigned short* __restrict__ cxt,
    unsigned short* __restrict__ tmpo, float* __restrict__ embo) {
  __shared__ unsigned short As[128 * 32];
  __shared__ unsigned short Bs[128 * 32];
  int bz = blockIdx.z;
  int bx = blockIdx.x;
  int em = (bx == 8);
  const unsigned short* A = St + (long)bz * 1048576;
  const unsigned short* B = em ? (cxt + (long)bz * 131072)
                               : (Badj + (long)bz * 1048576);
  int m0 = blockIdx.y * 128, n0 = em ? 0 : bx * 128;
  int tid = threadIdx.x, lane = tid & 63, w = tid >> 6;
  int wr = w >> 1, wc = w & 1;
  facc4 acc[4][4];
#pragma unroll
  for (int i = 0; i < 4; ++i)
#pragma unroll
    for (int j = 0; j < 4; ++j)
#pragma unroll
      for (int q = 0; q < 4; ++q) acc[i][j][q] = 0.f;

  int rA0 = w * 16 + (lane >> 2);
  int kslot = lane & 3;

  for (int k0 = 0; k0 < NN; k0 += 32) {
#pragma unroll
    for (int i = 0; i < 2; ++i) {
      int row = i * 64 + rA0;
      int ks = (kslot ^ (row & 3)) << 3;
      GLOAD16(A + (long)(m0 + row) * NN + k0 + ks, As + (i * 64 + w * 16) * 32);
      GLOAD16(B + (long)(n0 + row) * NN + k0 + ks, Bs + (i * 64 + w * 16) * 32);
    }
    __syncthreads();
    bfrag8 af[4], bfr[4];
#pragma unroll
    for (int mi = 0; mi < 4; ++mi) {
      int row = wr * 64 + mi * 16 + (lane & 15);
      int sl = (((lane >> 4) ^ (row & 3)) << 3);
      af[mi] = *(const bfrag8*)(As + row * 32 + sl);
    }
#pragma unroll
    for (int ni = 0; ni < 4; ++ni) {
      int row = wc * 64 + ni * 16 + (lane & 15);
      int sl = (((lane >> 4) ^ (row & 3)) << 3);
      bfr[ni] = *(const bfrag8*)(Bs + row * 32 + sl);
    }
#pragma unroll
    for (int mi = 0; mi < 4; ++mi)
#pragma unroll
      for (int ni = 0; ni < 4; ++ni)
        acc[mi][ni] = __builtin_amdgcn_mfma_f32_16x16x32_bf16(
            af[mi], bfr[ni], acc[mi][ni], 0, 0, 0);
    __syncthreads();
  }
#pragma unroll
  for (int mi = 0; mi < 4; ++mi) {
    int rowb = m0 + wr * 64 + mi * 16 + ((lane >> 4) << 2);
#pragma unroll
    for (int ni = 0; ni < 4; ++ni) {
      int col = n0 + wc * 64 + ni * 16 + (lane & 15);
#pragma unroll
      for (int q = 0; q < 4; ++q) {
        float v = acc[mi][ni][q];
        if (em)
          embo[(long)bz * 131072 + (long)(rowb + q) * HIDN + col] = v;
        else
          tmpo[(long)bz * 1048576 + (long)(rowb + q) * NN + col] = f2b(v);
      }
    }
  }
}

// ---- GCN MFMA: x = d_m*(sum_k A[m,k]*B[n,k] + d_m*XW[m,n]) + bias[n] -------
template<int SPLIT, int RELU>
__global__ __launch_bounds__(256) void k_mfma_gcn(
    const unsigned short* __restrict__ Ah, const unsigned short* __restrict__ Al,
    const unsigned short* __restrict__ Bh, const unsigned short* __restrict__ Bl,
    const float* __restrict__ dvv, const float* __restrict__ XW,
    const float* __restrict__ bias, float* __restrict__ Cf, int F) {
  __shared__ unsigned short AsH[128 * 32], BsH[128 * 32];
  __shared__ unsigned short AsL[SPLIT ? 128 * 32 : 16], BsL[SPLIT ? 128 * 32 : 16];
  int bz = blockIdx.z;
  const unsigned short* Ahb = Ah + (long)bz * NN * NN;
  const unsigned short* Alb = SPLIT ? Al + (long)bz * NN * NN : nullptr;
  const unsigned short* Bhb = Bh + (long)bz * F * NN;
  const unsigned short* Blb = SPLIT ? Bl + (long)bz * F * NN : nullptr;
  int m0 = blockIdx.y * 128, n0 = blockIdx.x * 128;
  int tid = threadIdx.x, lane = tid & 63, w = tid >> 6;
  int wr = w >> 1, wc = w & 1;
  facc4 acc[4][4];
#pragma unroll
  for (int i = 0; i < 4; ++i)
#pragma unroll
    for (int j = 0; j < 4; ++j)
#pragma unroll
      for (int q = 0; q < 4; ++q) acc[i][j][q] = 0.f;

  int rA0 = w * 16 + (lane >> 2);
  int kslot = lane & 3;

  for (int k0 = 0; k0 < NN; k0 += 32) {
#pragma unroll
    for (int i = 0; i < 2; ++i) {
      int row = i * 64 + rA0;
      int ks = (kslot ^ (row & 3)) << 3;
      int ld = (i * 64 + w * 16) * 32;
      GLOAD16(Ahb + (long)(m0 + row) * NN + k0 + ks, AsH + ld);
      GLOAD16(Bhb + (long)(n0 + row) * NN + k0 + ks, BsH + ld);
      if (SPLIT) {
        GLOAD16(Alb + (long)(m0 + row) * NN + k0 + ks, AsL + ld);
        GLOAD16(Blb + (long)(n0 + row) * NN + k0 + ks, BsL + ld);
      }
    }
    __syncthreads();
    bfrag8 afh[4], bfh[4], afl[4], bfl[4];
#pragma unroll
    for (int mi = 0; mi < 4; ++mi) {
      int row = wr * 64 + mi * 16 + (lane & 15);
      int sl = (((lane >> 4) ^ (row & 3)) << 3);
      afh[mi] = *(const bfrag8*)(AsH + row * 32 + sl);
      if (SPLIT) afl[mi] = *(const bfrag8*)(AsL + row * 32 + sl);
    }
#pragma unroll
    for (int ni = 0; ni < 4; ++ni) {
      int row = wc * 64 + ni * 16 + (lane & 15);
      int sl = (((lane >> 4) ^ (row & 3)) << 3);
      bfh[ni] = *(const bfrag8*)(BsH + row * 32 + sl);
      if (SPLIT) bfl[ni] = *(const bfrag8*)(BsL + row * 32 + sl);
    }
#pragma unroll
    for (int mi = 0; mi < 4; ++mi)
#pragma unroll
      for (int ni = 0; ni < 4; ++ni) {
        acc[mi][ni] = __builtin_amdgcn_mfma_f32_16x16x32_bf16(
            afh[mi], bfh[ni], acc[mi][ni], 0, 0, 0);
        if (SPLIT) {
          acc[mi][ni] = __builtin_amdgcn_mfma_f32_16x16x32_bf16(
              afh[mi], bfl[ni], acc[mi][ni], 0, 0, 0);
          acc[mi][ni] = __builtin_amdgcn_mfma_f32_16x16x32_bf16(
              afl[mi], bfh[ni], acc[mi][ni], 0, 0, 0);
        }
      }
    __syncthreads();
  }
  Cf += (long)bz * NN * F;
#pragma unroll
  for (int mi = 0; mi < 4; ++mi) {
    int rowb = m0 + wr * 64 + mi * 16 + ((lane >> 4) << 2);
#pragma unroll
    for (int ni = 0; ni < 4; ++ni) {
      int col = n0 + wc * 64 + ni * 16 + (lane & 15);
      float bcol = bias[col];
#pragma unroll
      for (int q = 0; q < 4; ++q) {
        float dm = dvv[(bz << 10) + rowb + q];
        float xwv = XW[((long)(bz << 10) + rowb + q) * F + col];
        float v = dm * (acc[mi][ni][q] + dm * xwv) + bcol;
        if (RELU) v = fmaxf(v, 0.f);
        Cf[(long)(rowb + q) * F + col] = v;
      }
    }
  }
}

// ---- split-bf16 3-product NT MFMA Gram + fused C^T write -------------------
__global__ __launch_bounds__(256) void k_mfma_gram(
    const unsigned short* __restrict__ Ah, const unsigned short* __restrict__ Al,
    const unsigned short* __restrict__ Bh, const unsigned short* __restrict__ Bl,
    const float* __restrict__ xx, const float* __restrict__ yy,
    float* __restrict__ Cf, float* __restrict__ Ct) {
  __shared__ unsigned short AsH[128 * 32], AsL[128 * 32];
  __shared__ unsigned short BsH[128 * 32], BsL[128 * 32];
  int bz = blockIdx.z;
  long boff = (long)bz * NN * FIN;
  Ah += boff; Al += boff; Bh += boff; Bl += boff;
  const float* xxb = xx + (bz << 10);
  const float* yyb = yy + (bz << 10);
  int m0 = blockIdx.y * 128, n0 = blockIdx.x * 128;
  int tid = threadIdx.x, lane = tid & 63, w = tid >> 6;
  int wr = w >> 1, wc = w & 1;
  facc4 acc[4][4];
#pragma unroll
  for (int i = 0; i < 4; ++i)
#pragma unroll
    for (int j = 0; j < 4; ++j)
#pragma unroll
      for (int q = 0; q < 4; ++q) acc[i][j][q] = 0.f;

  int rA0 = w * 16 + (lane >> 2);
  int kslot = lane & 3;

  for (int k0 = 0; k0 < FIN; k0 += 32) {
#pragma unroll
    for (int i = 0; i < 2; ++i) {
      int row = i * 64 + rA0;
      int ks = (kslot ^ (row & 3)) << 3;
      long ga = (long)(m0 + row) * FIN + k0 + ks;
      long gb = (long)(n0 + row) * FIN + k0 + ks;
      int ld = (i * 64 + w * 16) * 32;
      GLOAD16(Ah + ga, AsH + ld);
      GLOAD16(Al + ga, AsL + ld);
      GLOAD16(Bh + gb, BsH + ld);
      GLOAD16(Bl + gb, BsL + ld);
    }
    __syncthreads();
    bfrag8 afh[4], afl[4], bfh[4], bfl[4];
#pragma unroll
    for (int mi = 0; mi < 4; ++mi) {
      int row = wr * 64 + mi * 16 + (lane & 15);
      int sl = (((lane >> 4) ^ (row & 3)) << 3);
      afh[mi] = *(const bfrag8*)(AsH + row * 32 + sl);
      afl[mi] = *(const bfrag8*)(AsL + row * 32 + sl);
    }
#pragma unroll
    for (int ni = 0; ni < 4; ++ni) {
      int row = wc * 64 + ni * 16 + (lane & 15);
      int sl = (((lane >> 4) ^ (row & 3)) << 3);
      bfh[ni] = *(const bfrag8*)(BsH + row * 32 + sl);
      bfl[ni] = *(const bfrag8*)(BsL + row * 32 + sl);
    }
#pragma unroll
    for (int mi = 0; mi < 4; ++mi)
#pragma unroll
      for (int ni = 0; ni < 4; ++ni) {
        acc[mi][ni] = __builtin_amdgcn_mfma_f32_16x16x32_bf16(
            afh[mi], bfh[ni], acc[mi][ni], 0, 0, 0);
        acc[mi][ni] = __builtin_amdgcn_mfma_f32_16x16x32_bf16(
            afh[mi], bfl[ni], acc[mi][ni], 0, 0, 0);
        acc[mi][ni] = __builtin_amdgcn_mfma_f32_16x16x32_bf16(
            afl[mi], bfh[ni], acc[mi][ni], 0, 0, 0);
      }
    __syncthreads();
  }
  Cf += (long)bz * NN * NN;
  Ct += (long)bz * NN * NN;
#pragma unroll
  for (int mi = 0; mi < 4; ++mi) {
    int rowb = m0 + wr * 64 + mi * 16 + ((lane >> 4) << 2);
#pragma unroll
    for (int ni = 0; ni < 4; ++ni) {
      int col = n0 + wc * 64 + ni * 16 + (lane & 15);
      float yv = yyb[col];
      float4 tv;
#pragma unroll
      for (int q = 0; q < 4; ++q) {
        float v = xxb[rowb + q] + yv - 2.f * acc[mi][ni][q];
        Cf[(long)(rowb + q) * NN + col] = v;
        ((float*)&tv)[q] = v;
      }
      *(float4*)(Ct + (long)col * NN + rowb) = tv;   // transposed write
    }
  }
}

// ---------------- s0 = cx @ Watt  (per-row dot, HID=128) --------------------
__global__ __launch_bounds__(256) void k_rowdot(const float* __restrict__ X,
                                                const float* __restrict__ w,
                                                float* __restrict__ out) {
  int t = threadIdx.x; int lane = t & 63; int wv = t >> 6;
  int row = blockIdx.x * 4 + wv;
  const float* xr = X + (long)row * HIDN;
  float s = xr[lane] * w[lane] + xr[lane + 64] * w[lane + 64];
  s = wred_sum(s);
  if (lane == 0) out[row] = s;
}

// ---- alpha (4 rows/block) from bf16 adj ------------------------------------
__global__ __launch_bounds__(256) void k_alpha4b(const unsigned short* __restrict__ adj,
                                                 const float* __restrict__ dv,
                                                 const float* __restrict__ s0,
                                                 const float* __restrict__ batt,
                                                 float* __restrict__ alpha) {
  int r0 = blockIdx.x << 2; int b = r0 >> 10; int i0 = r0 & (NN - 1);
  int t = threadIdx.x, lane = t & 63, wv = t >> 6;
  float4 d4 = ((const float4*)(dv + (b << 10)))[t];
  float4 s4 = ((const float4*)(s0 + (b << 10)))[t];
  float w4[4];
  w4[0] = d4.x * s4.x; w4[1] = d4.y * s4.y; w4[2] = d4.z * s4.z; w4[3] = d4.w * s4.w;
  __shared__ float sm[4][4];
#pragma unroll
  for (int r = 0; r < 4; ++r) {
    ushort4 h = ((const ushort4*)(adj + (long)(r0 + r) * NN))[t];
    float dot = b2f(h.x) * w4[0] + b2f(h.y) * w4[1] +
                b2f(h.z) * w4[2] + b2f(h.w) * w4[3];
    int i = i0 + r;
    if ((i >> 2) == t) dot += w4[i & 3];   // +I diagonal
    dot = wred_sum(dot);
    if (lane == 0) sm[wv][r] = dot;
  }
  __syncthreads();
  if (t < 4) {
    float dot = sm[0][t] + sm[1][t] + sm[2][t] + sm[3][t];
    float tt = dv[r0 + t] * dot + batt[0];
    alpha[r0 + t] = 1.f / (1.f + __expf(-tt * tt));
  }
}

// ---- per-batch k-th largest via 8-bit radix select --------------------------
// alpha > 0 so uint ordering == float ordering. Exact (duplicate-correct).
__global__ __launch_bounds__(512) void k_topk(const float* __restrict__ alpha,
                                              float* __restrict__ cut) {
  int b = blockIdx.x, t = threadIdx.x;
  unsigned e0 = __float_as_uint(alpha[(b << 10) + t]);
  unsigned e1 = __float_as_uint(alpha[(b << 10) + t + 512]);
  __shared__ int hist[256];
  __shared__ unsigned pref;
  __shared__ int kk;
  if (t == 0) { pref = 0u; kk = KTOP; }
  __syncthreads();
  for (int pass = 0; pass < 4; ++pass) {
    int shift = 24 - pass * 8;
    if (t < 256) hist[t] = 0;
    __syncthreads();
    unsigned p = pref; int k = kk;
    if (pass == 0 || (e0 >> (shift + 8)) == p)
      atomicAdd(&hist[(e0 >> shift) & 255], 1);
    if (pass == 0 || (e1 >> (shift + 8)) == p)
      atomicAdd(&hist[(e1 >> shift) & 255], 1);
    __syncthreads();
    if (t < 64) {   // single-wave suffix scan over 256 bins (4 bins/lane)
      int h0 = hist[4 * t], h1 = hist[4 * t + 1];
      int h2 = hist[4 * t + 2], h3 = hist[4 * t + 3];
      int s3 = h3, s2 = h2 + s3, s1 = h1 + s2, s0 = h0 + s1;
      int T = s0, tin = T;
#pragma unroll
      for (int off = 1; off < 64; off <<= 1) {
        int v = __shfl_down(tin, off);
        if (t + off < 64) tin += v;
      }
      int above = tin - T;   // sum over lanes > t
      int suf0 = s0 + above, suf1 = s1 + above;
      int suf2 = s2 + above, suf3 = s3 + above, sufN = above;
      if (suf0 >= k && suf1 < k) { pref = (p << 8) | (unsigned)(4 * t + 0); kk = k - suf1; }
      if (suf1 >= k && suf2 < k) { pref = (p << 8) | (unsigned)(4 * t + 1); kk = k - suf2; }
      if (suf2 >= k && suf3 < k) { pref = (p << 8) | (unsigned)(4 * t + 2); kk = k - suf3; }
      if (suf3 >= k && sufN < k) { pref = (p << 8) | (unsigned)(4 * t + 3); kk = k - sufN; }
    }
    __syncthreads();
  }
  if (t == 0) cut[b] = __uint_as_float(pref);
}

// ---- S build (4 rows/block) from bf16 adj ----------------------------------
__global__ __launch_bounds__(256) void k_sbuild4b(const unsigned short* __restrict__ adj,
                                                  const float* __restrict__ dv,
                                                  const float* __restrict__ rm,
                                                  const float* __restrict__ alpha,
                                                  const float* __restrict__ cut,
                                                  float* __restrict__ S) {
  int r0 = blockIdx.x << 2; int b = r0 >> 10; int i0 = r0 & (NN - 1);
  int t = threadIdx.x, lane = t & 63, wv = t >> 6;
  float cb = cut[b];
  float4 d4 = ((const float4*)(dv + (b << 10)))[t];
  float4 al4 = ((const float4*)(alpha + (b << 10)))[t];
  float4 dg;
  dg.x = d4.x * fmaxf(al4.x + 1e-7f - cb, 0.f);
  dg.y = d4.y * fmaxf(al4.y + 1e-7f - cb, 0.f);
  dg.z = d4.z * fmaxf(al4.z + 1e-7f - cb, 0.f);
  dg.w = d4.w * fmaxf(al4.w + 1e-7f - cb, 0.f);
  __shared__ float sm[4][4];
  __shared__ float sinv[4];
  float4 vals[4];
#pragma unroll
  for (int r = 0; r < 4; ++r) {
    float di = dv[r0 + r] * rm[r0 + r];
    ushort4 h = ((const ushort4*)(adj + (long)(r0 + r) * NN))[t];
    float4 a4;
    a4.x = b2f(h.x); a4.y = b2f(h.y); a4.z = b2f(h.z); a4.w = b2f(h.w);
    int i = i0 + r;
    if ((i >> 2) == t) ((float*)&a4)[i & 3] += 1.f;
    vals[r].x = di * dg.x * a4.x; vals[r].y = di * dg.y * a4.y;
    vals[r].z = di * dg.z * a4.z; vals[r].w = di * dg.w * a4.w;
    float s = (fabsf(vals[r].x) + fabsf(vals[r].y)) +
              (fabsf(vals[r].z) + fabsf(vals[r].w));
    s = wred_sum(s);
    if (lane == 0) sm[wv][r] = s;
  }
  __syncthreads();
  if (t < 4) sinv[t] = 1.f / fmaxf(sm[0][t] + sm[1][t] + sm[2][t] + sm[3][t], 1e-12f);
  __syncthreads();
#pragma unroll
  for (int r = 0; r < 4; ++r) {
    float inv = sinv[r];
    float4 o; o.x = vals[r].x * inv; o.y = vals[r].y * inv;
    o.z = vals[r].z * inv; o.w = vals[r].w * inv;
    ((float4*)(S + (long)(r0 + r) * NN))[t] = o;
  }
}

// ---------------- K-split fp32 GEMM (TA=0,TB=0), partials out ---------------
template<int GCN>
__global__ __launch_bounds__(256) void k_gemm_ks(
    const float* __restrict__ A, const float* __restrict__ Bm, float* __restrict__ P,
    int M, int Nn, int K, int KS, long sA, long sB,
    const float* __restrict__ dv) {
  __shared__ float As[8][132];
  __shared__ float Bs[8][132];
  int z = blockIdx.z;
  int b = z / KS, ks = z % KS;
  int KC = K / KS;
  A += (long)b * sA; Bm += (long)b * sB;
  const float* dvb = GCN ? (dv + (long)b * NN) : nullptr;
  int m0 = blockIdx.y * 128, n0 = blockIdx.x * 128;
  int tid = threadIdx.x;
  int tx = tid & 15, ty = tid >> 4;
  float acc[8][8];
#pragma unroll
  for (int i = 0; i < 8; i++)
#pragma unroll
    for (int j = 0; j < 8; j++) acc[i][j] = 0.f;

  float drow = 0.f;
  if (GCN) drow = dvb[m0 + (tid >> 1)];

  for (int k0 = ks * KC; k0 < ks * KC + KC; k0 += 8) {
    {
      int r = tid >> 1, c4 = (tid & 1) * 4;
      float4 av = *(const float4*)(A + (long)(m0 + r) * K + k0 + c4);
      float a4[4] = {av.x, av.y, av.z, av.w};
      if (GCN) {
#pragma unroll
        for (int q = 0; q < 4; ++q) {
          int gj = k0 + c4 + q;
          float val = a4[q] + ((m0 + r) == gj ? 1.f : 0.f);
          a4[q] = drow * dvb[gj] * val;
        }
      }
      As[c4 + 0][r] = a4[0]; As[c4 + 1][r] = a4[1];
      As[c4 + 2][r] = a4[2]; As[c4 + 3][r] = a4[3];
    }
    {
      int kr = tid >> 5, c4 = (tid & 31) * 4;
      float4 bv = *(const float4*)(Bm + (long)(k0 + kr) * Nn + n0 + c4);
      *(float4*)&Bs[kr][c4] = bv;
    }
    __syncthreads();
#pragma unroll
    for (int k = 0; k < 8; ++k) {
      float av[8], bv[8];
      *(float4*)&av[0] = *(const float4*)&As[k][ty * 8];
      *(float4*)&av[4] = *(const float4*)&As[k][ty * 8 + 4];
      *(float4*)&bv[0] = *(const float4*)&Bs[k][tx * 8];
      *(float4*)&bv[4] = *(const float4*)&Bs[k][tx * 8 + 4];
#pragma unroll
      for (int i = 0; i < 8; i++)
#pragma unroll
        for (int j = 0; j < 8; j++)
          acc[i][j] = fmaf(av[i], bv[j], acc[i][j]);
    }
    __syncthreads();
  }
  float* Pz = P + (long)z * M * Nn;
#pragma unroll
  for (int i = 0; i < 8; ++i) {
    int m = m0 + ty * 8 + i;
    float* prow = Pz + (long)m * Nn + n0 + tx * 8;
    *(float4*)&prow[0] = *(float4*)&acc[i][0];
    *(float4*)&prow[4] = *(float4*)&acc[i][4];
  }
}

// ---------------- reduce K-split partials (+bias, +relu) --------------------
template<int RELU, int BIAS>
__global__ __launch_bounds__(256) void k_red_bias(
    const float* __restrict__ P, const float* __restrict__ bias,
    float* __restrict__ out, int Nn, int KS, long chunk) {
  long u = ((long)blockIdx.x * 256 + threadIdx.x) * 4;
  long b = u / chunk; long rem = u % chunk;
  const float* p = P + b * KS * chunk + rem;
  float4 s = *(const float4*)p;
  for (int k = 1; k < KS; ++k) {
    float4 q = *(const float4*)(p + (long)k * chunk);
    s.x += q.x; s.y += q.y; s.z += q.z; s.w += q.w;
  }
  if (BIAS) {
    int n = (int)(rem % Nn);
    s.x += bias[n]; s.y += bias[n + 1]; s.z += bias[n + 2]; s.w += bias[n + 3];
  }
  if (RELU) {
    s.x = fmaxf(s.x, 0.f); s.y = fmaxf(s.y, 0.f);
    s.z = fmaxf(s.z, 0.f); s.w = fmaxf(s.w, 0.f);
  }
  *(float4*)(out + u) = s;
}

// ---------------- column mean over nodes ------------------------------------
__global__ __launch_bounds__(256) void k_colmean(const float* __restrict__ X, int Fd,
                                                 float* __restrict__ out) {
  int nb = Fd >> 6;
  int b = blockIdx.x / nb; int f0 = (blockIdx.x % nb) << 6;
  int t = threadIdx.x;
  int f = f0 + (t & 63); int rc = t >> 6;
  const float* xb = X + (long)b * NN * Fd;
  float s = 0.f;
  for (int i = rc * 256; i < rc * 256 + 256; ++i) s += xb[(long)i * Fd + f];
  __shared__ float sm[256];
  sm[t] = s; __syncthreads();
  if (t < 64) out[b * Fd + f] = (sm[t] + sm[t + 64] + sm[t + 128] + sm[t + 192]) * (1.f / NN);
}

// ======================= persistent register-resident Sinkhorn ==============
// Sentinel barrier (data IS the flag); dual stores are now fire-and-forget
// (no vmcnt wait — visibility is the only requirement, each value written
// once). LLC (sc0 sc1) coherence. Defer-max with self-correcting refresh.

static __device__ __forceinline__ float2 load_cohere2(const float* p) {
  float2 v;
  asm volatile("global_load_dwordx2 %0, %1, off sc0 sc1\n\ts_waitcnt vmcnt(0)"
               : "=v"(v) : "v"(p) : "memory");
  return v;
}
static __device__ __forceinline__ float load_cohere1(const float* p) {
  float v;
  asm volatile("global_load_dword %0, %1, off sc0 sc1\n\ts_waitcnt vmcnt(0)"
               : "=v"(v) : "v"(p) : "memory");
  return v;
}
static __device__ __forceinline__ void dstore_ff(float* p, float v) {
  asm volatile("global_store_dword %0, %1, off sc0 sc1"
               :: "v"(p), "v"(v) : "memory");
}
static __device__ __forceinline__ void store_cohere1(float* p, float v) {
  asm volatile("global_store_dword %0, %1, off sc0 sc1\n\ts_waitcnt vmcnt(0)"
               :: "v"(p), "v"(v) : "memory");
}

// Poll db[g] slice (2 floats/thread) until non-sentinel, then stage into LDS.
static __device__ __forceinline__ void pollstage(const float* __restrict__ src,
                                                 float* __restrict__ vls, int t) {
  float2 v; int spin = 0;
  for (;;) {
    v = load_cohere2(src + t * 2);
    if ((__float_as_uint(v.x) != SENTU) & (__float_as_uint(v.y) != SENTU)) break;
    if (++spin > (1 << 20)) break;
    __builtin_amdgcn_s_sleep(1);
  }
  __syncthreads();                  // all waves done reading old vls
  *(float2*)(vls + t * 2) = v;
  __syncthreads();
}

// One LSE half-pass for this lane's interleaved row slice.
template<int LOSS, int STORE>
static __device__ __forceinline__ void pass_reg(const float4 (&Cr)[16],
    const float* __restrict__ vls, float* __restrict__ dbout,
    int jc, int row, float* __restrict__ lossacc, float& mxs, int fresh) {
  float4 vr[16];
#pragma unroll
  for (int k = 0; k < 16; ++k)
    vr[k] = *(const float4*)(vls + (k * 16 + jc) * 4);
  float mx = mxs;
  if (fresh) {
    float m0 = -3.0e38f, m1 = m0, m2 = m0, m3 = m0;
#pragma unroll
    for (int k = 0; k < 16; ++k) {
      m0 = fmaxf(m0, vr[k].x - Cr[k].x);
      m1 = fmaxf(m1, vr[k].y - Cr[k].y);
      m2 = fmaxf(m2, vr[k].z - Cr[k].z);
      m3 = fmaxf(m3, vr[k].w - Cr[k].w);
    }
    mx = fmaxf(fmaxf(m0, m1), fmaxf(m2, m3));
#pragma unroll
    for (int m = 1; m <= 8; m <<= 1) mx = fmaxf(mx, __shfl_xor(mx, m));
  }
  float ls, ld = 0.f;
  {
    float s0 = 0, s1 = 0, s2 = 0, s3 = 0, d0 = 0, d1 = 0, d2 = 0, d3 = 0;
#pragma unroll
    for (int k = 0; k < 16; ++k) {
      float e0 = __expf(vr[k].x - Cr[k].x - mx);
      float e1 = __expf(vr[k].y - Cr[k].y - mx);
      float e2 = __expf(vr[k].z - Cr[k].z - mx);
      float e3 = __expf(vr[k].w - Cr[k].w - mx);
      s0 += e0; s1 += e1; s2 += e2; s3 += e3;
      if (LOSS) {
        d0 = fmaf(e0, Cr[k].x, d0); d1 = fmaf(e1, Cr[k].y, d1);
        d2 = fmaf(e2, Cr[k].z, d2); d3 = fmaf(e3, Cr[k].w, d3);
      }
    }
    ls = (s0 + s1) + (s2 + s3);
    if (LOSS) ld = (d0 + d1) + (d2 + d3);
  }
#pragma unroll
  for (int m = 1; m <= 8; m <<= 1) {
    ls += __shfl_xor(ls, m);
    if (LOSS) ld += __shfl_xor(ld, m);
  }
  if (!(ls > 1e-25f && ls < 1e25f)) {       // stale max -> refresh + redo
    float m0 = -3.0e38f, m1 = m0, m2 = m0, m3 = m0;
#pragma unroll
    for (int k = 0; k < 16; ++k) {
      m0 = fmaxf(m0, vr[k].x - Cr[k].x);
      m1 = fmaxf(m1, vr[k].y - Cr[k].y);
      m2 = fmaxf(m2, vr[k].z - Cr[k].z);
      m3 = fmaxf(m3, vr[k].w - Cr[k].w);
    }
    mx = fmaxf(fmaxf(m0, m1), fmaxf(m2, m3));
#pragma unroll
    for (int m = 1; m <= 8; m <<= 1) mx = fmaxf(mx, __shfl_xor(mx, m));
    float s0 = 0, s1 = 0, s2 = 0, s3 = 0, d0 = 0, d1 = 0, d2 = 0, d3 = 0;
#pragma unroll
    for (int k = 0; k < 16; ++k) {
      float e0 = __expf(vr[k].x - Cr[k].x - mx);
      float e1 = __expf(vr[k].y - Cr[k].y - mx);
      float e2 = __expf(vr[k].z - Cr[k].z - mx);
      float e3 = __expf(vr[k].w - Cr[k].w - mx);
      s0 += e0; s1 += e1; s2 += e2; s3 += e3;
      if (LOSS) {
        d0 = fmaf(e0, Cr[k].x, d0); d1 = fmaf(e1, Cr[k].y, d1);
        d2 = fmaf(e2, Cr[k].z, d2); d3 = fmaf(e3, Cr[k].w, d3);
      }
    }
    ls = (s0 + s1) + (s2 + s3);
    if (LOSS) ld = (d0 + d1) + (d2 + d3);
#pragma unroll
    for (int m = 1; m <= 8; m <<= 1) {
      ls += __shfl_xor(ls, m);
      if (LOSS) ld += __shfl_xor(ld, m);
    }
  }
  mxs = mx;
  if (jc == 0) {
    float uval = LOG_MU - (mx + __logf(ls));   // scaled dual u/eps
    if (STORE) dstore_ff(dbout + row, uval);
    if (LOSS) *lossacc += (ld / ls) * (1.0f / 1024.0f);
  }
}

__global__ __launch_bounds__(512, 1) void k_sink_reg(
    const float* __restrict__ Cm, const float* __restrict__ Ct,
    float* __restrict__ db, float* __restrict__ part,
    float* __restrict__ oloss) {
  int bid = blockIdx.x, t = threadIdx.x, lane = t & 63, wvi = t >> 6;
  int jc = lane & 15;
  int grp = bid & 7;          // batch index
  int inner = bid >> 3;       // 0..31
  int row = (grp << 10) + inner * 32 + wvi * 4 + (lane >> 4);
  __shared__ float vls[1024];
  float4 Creg[16], Ctreg[16];
  {
    const float4* cp = (const float4*)(Cm + (long)row * NN);
    const float4* tp = (const float4*)(Ct + (long)row * NN);
#pragma unroll
    for (int k = 0; k < 16; ++k) {
      float4 c = cp[k * 16 + jc], ct = tp[k * 16 + jc];
      Creg[k].x = c.x * INV_EPS;  Creg[k].y = c.y * INV_EPS;
      Creg[k].z = c.z * INV_EPS;  Creg[k].w = c.w * INV_EPS;
      Ctreg[k].x = ct.x * INV_EPS; Ctreg[k].y = ct.y * INV_EPS;
      Ctreg[k].z = ct.z * INV_EPS; Ctreg[k].w = ct.w * INV_EPS;
    }
  }
  // stage db[0] (initial v = zeros) into LDS
  {
    float2 v = *(const float2*)(db + (grp << 10) + t * 2);
    *(float2*)(vls + t * 2) = v;
  }
  __syncthreads();
  float lossacc = 0.f;
  float mxu = 0.f, mxv = 0.f;
  int g = 1;
  for (int it = 0; it < NITER; ++it) {
    pass_reg<0, 1>(Creg, vls, db + (long)g * 8192, jc, row, nullptr, mxu, it == 0);
    pollstage(db + (long)g * 8192 + (grp << 10), vls, t);
    ++g;
    if (it < NITER - 1) {
      pass_reg<0, 1>(Ctreg, vls, db + (long)g * 8192, jc, row, nullptr, mxv, it == 0);
      pollstage(db + (long)g * 8192 + (grp << 10), vls, t);
      ++g;
    } else {
      pass_reg<1, 0>(Ctreg, vls, nullptr, jc, row, &lossacc, mxv, 0);
    }
  }
  // per-block loss partial (data-sentinel handoff)
  float s = wred_sum(lossacc);
  __shared__ float lsm[8];
  if (lane == 0) lsm[wvi] = s;
  __syncthreads();
  if (t == 0) {
    float ps = 0.f;
#pragma unroll
    for (int i = 0; i < 8; ++i) ps += lsm[i];
    store_cohere1(part + bid, ps);
  }
  if (bid == 0) {
    float s2 = 0.f;
    if (t < SNB) {
      int spin = 0;
      for (;;) {
        s2 = load_cohere1(part + t);
        if (__float_as_uint(s2) != SENTU) break;
        if (++spin > (1 << 20)) { s2 = 0.f; break; }
        __builtin_amdgcn_s_sleep(1);
      }
    }
    s2 = wred_sum(s2);
    __shared__ float sm2[8];
    if (lane == 0) sm2[wvi] = s2;
    __syncthreads();
    if (t == 0) {
      float tot = 0.f;
#pragma unroll
      for (int i = 0; i < 8; ++i) tot += sm2[i];
      oloss[0] = tot * EPS_S;   // undo the 1/eps scaling of C' in ld
    }
  }
}

extern "C" void kernel_launch(void* const* d_in, const int* in_sizes, int n_in,
                              void* d_out, int out_size, void* d_ws, size_t ws_size,
                              hipStream_t stream) {
  const float* x    = (const float*)d_in[0];
  const float* adj  = (const float*)d_in[1];
  const float* W1   = (const float*)d_in[3];
  const float* b1   = (const float*)d_in[4];
  const float* Watt = (const float*)d_in[5];
  const float* batt = (const float*)d_in[6];
  const float* W2   = (const float*)d_in[7];
  const float* b2   = (const float*)d_in[8];

  float* out = (float*)d_out;
  float* xs0   = out;                    // [8,128]
  float* xs1   = out + 1024;             // [8,256]
  float* oadj0 = out + 3072;             // [8,1024,1024]
  float* oadj1 = oadj0 + 8388608;
  float* oadj2 = oadj1 + 8388608;        // adj_bf scratch until adj2 written
  float* oS0   = oadj2 + 8388608;
  float* oS1   = oS0 + 8388608;
  float* oloss = oS1 + 8388608;          // [1]

  float* ws   = (float*)d_ws;
  float* wXW  = ws;                       // 2,097,152 (XW1 then XW2)
  float* wCXA = wXW + 2097152;            // 1,048,576 (x1, later emb2)
  float* wCXB = wCXA + 1048576;           // 1,048,576 (emb1)
  float* wR   = wCXB + 1048576;           // 8,388,608 (tmp_bf | P | Cmat)
  float* wX2  = wR + 8388608;             // 2,097,152 (x2)
  float* wStf = wX2 + 2097152;            // 4,194,304 (x_bf/St/Bg2/x-splits)
  float* wCxtf= wStf + 4194304;           // 524,288   (Bg1 / cxt)
  float* wCt  = wCxtf + 524288;           // 8,388,608 (a2h+a2l, then C^T)
  float* smb  = wCt + 8388608;

  unsigned short* tmp_bf = (unsigned short*)wR;                 // 16.7MB half
  unsigned short* a2h    = (unsigned short*)wCt;                // 8,388,608 sh
  unsigned short* a2l    = a2h + 8388608;                       // 8,388,608 sh
  unsigned short* adj_bf = (unsigned short*)oadj2;
  unsigned short* St     = (unsigned short*)wStf;
  unsigned short* cxt    = (unsigned short*)wCxtf;
  unsigned short* x_bf   = (unsigned short*)wStf;               // pre-coarsen
  unsigned short* Bg1    = (unsigned short*)wCxtf;
  unsigned short* Bg2h   = (unsigned short*)wStf;               // post-adj2
  unsigned short* Bg2l   = (unsigned short*)(wStf + 2097152);
  unsigned short* xh  = (unsigned short*)wStf;                  // sinkhorn phase
  unsigned short* xl  = xh + 2097152;
  unsigned short* x2h = xh + 4194304;
  unsigned short* x2l = xh + 6291456;
  float* Cmat = wR;
  float* d0 = smb;            float* rm0 = smb + 8192;
  float* d1 = smb + 16384;    float* rm1 = smb + 24576;
  float* d2 = smb + 32768;    float* rm2 = smb + 40960;
  float* s0v = smb + 49152;   float* alp = smb + 57344;
  float* xxv = smb + 65536;   float* yyv = smb + 73728;
  float* cutv = smb + 98304;  float* part = smb + 98368;  // 256
  unsigned short* W1t = (unsigned short*)(smb + 98624);    // 32768 shorts
  float* db = smb + 131072;    // 41*8192 floats: dual generations
  float* rowsum1 = smb + 131072 + 41 * 8192;               // 8192
  float* rowsum2 = rowsum1 + 8192;                         // 8192

  // ---- sentinel/init memsets first (off critical path) ----
  hipMemsetAsync(db, 0, (size_t)8192 * 4, stream);                 // db[0]=v0=0
  hipMemsetAsync(db + 8192, 0xFF, (size_t)40 * 8192 * 4, stream);  // sentinels
  hipMemsetAsync(part, 0xFF, (size_t)256 * 4, stream);             // sentinels
  hipMemsetAsync(rowsum1, 0, (size_t)16384 * 4, stream);           // both rowsums

  // rowstats on adj + fused bf16 copy (into oadj2 region) + fp32 copy (oadj0)
  k_rowstats4<1, 1><<<2048, 256, 0, stream>>>(adj, d0, rm0, adj_bf, oadj0);

  // ---- GCN1 (MFMA): x1 = relu(d*(adj_bf @ (d.*XW1) + d*XW1_diag) + b1) ----
  k_f2b<<<2048, 256, 0, stream>>>(x, x_bf);
  k_w1t<<<128, 256, 0, stream>>>(W1, W1t);
  k_mfma_nt<1, 0, 0><<<dim3(1, 64, 1), 256, 0, stream>>>(x_bf, W1t, wXW, nullptr,
      nullptr, 256, 256, 256, 128, 0L, 0L, 0L, nullptr);
  k_stc<0><<<dim3(16, 2, 8), 256, 0, stream>>>(wXW, d0, Bg1, nullptr, HIDN);
  k_mfma_gcn<0, 1><<<dim3(1, 8, 8), 256, 0, stream>>>(adj_bf, nullptr, Bg1,
      nullptr, d0, wXW, b1, wCXA, HIDN);
  k_colmean<<<16, 256, 0, stream>>>(wCXA, HIDN, xs0);

  // ---- coarsen layer 1 (bf16 adj reads) ----
  k_rowdot<<<2048, 256, 0, stream>>>(wCXA, Watt, s0v);
  k_alpha4b<<<2048, 256, 0, stream>>>(adj_bf, d0, s0v, batt, alp);
  k_topk<<<8, 512, 0, stream>>>(alp, cutv);
  k_sbuild4b<<<2048, 256, 0, stream>>>(adj_bf, d0, rm0, alp, cutv, oS0);
  k_transp<<<dim3(16, 16, 8), 256, 0, stream>>>(oS0, St, 1024, 1024);
  k_transp<<<dim3(2, 16, 8), 256, 0, stream>>>(wCXA, cxt, 1024, 128);
  k_coars<<<dim3(9, 8, 8), 256, 0, stream>>>(St, adj_bf, cxt, tmp_bf, wCXB);
  // adj1 GEMM with fused rowsum accumulation
  k_mfma_nt<1, 1, 1><<<dim3(8, 8, 8), 256, 0, stream>>>(tmp_bf, St, oadj1, adj_bf,
      nullptr, 1024, 1024, 1024, 1024, 1048576L, 1048576L, 1048576L, rowsum1);
  k_dfrom<<<32, 256, 0, stream>>>(rowsum1, d1, rm1);

  // ---- coarsen layer 2 (bf16 adj1 reads) ----
  k_rowdot<<<2048, 256, 0, stream>>>(wCXB, Watt, s0v);
  k_alpha4b<<<2048, 256, 0, stream>>>(adj_bf, d1, s0v, batt, alp);
  k_topk<<<8, 512, 0, stream>>>(alp, cutv);
  k_sbuild4b<<<2048, 256, 0, stream>>>(adj_bf, d1, rm1, alp, cutv, oS1);
  k_transp<<<dim3(16, 16, 8), 256, 0, stream>>>(oS1, St, 1024, 1024);
  k_transp<<<dim3(2, 16, 8), 256, 0, stream>>>(wCXB, cxt, 1024, 128);
  k_coars<<<dim3(9, 8, 8), 256, 0, stream>>>(St, adj_bf, cxt, tmp_bf, wCXA);
  // adj2 GEMM with fused rowsum accumulation
  k_mfma_nt<1, 2, 1><<<dim3(8, 8, 8), 256, 0, stream>>>(tmp_bf, St, oadj2, a2h,
      a2l, 1024, 1024, 1024, 1024, 1048576L, 1048576L, 1048576L, rowsum2);
  k_dfrom<<<32, 256, 0, stream>>>(rowsum2, d2, rm2);

  // ---- final GCN (split-bf16 MFMA): x2 = d*(A2@(d.*XW2) + d*XW2_diag) + b2 --
  k_gemm_ks<0><<<dim3(2, 64, 2), 256, 0, stream>>>(wCXA, W2, wR, 8192, FIN, HIDN,
      2, 0L, 0L, nullptr);   // P partials in wR first half (tmp_bf dead)
  k_red_bias<0, 0><<<2048, 256, 0, stream>>>(wR, nullptr, wXW, FIN, 2, 2097152L);
  k_stc<1><<<dim3(16, 4, 8), 256, 0, stream>>>(wXW, d2, Bg2h, Bg2l, FIN);
  k_mfma_gcn<1, 0><<<dim3(2, 8, 8), 256, 0, stream>>>(a2h, a2l, Bg2h, Bg2l,
      d2, wXW, b2, wX2, FIN);
  k_colmean<<<32, 256, 0, stream>>>(wX2, FIN, xs1);

  // ---- Sinkhorn: C via split-bf16 MFMA Gram (+fused C^T), reg-resident solve
  k_prep2<<<4096, 256, 0, stream>>>(x, wX2, xh, xl, x2h, x2l, xxv, yyv);
  k_mfma_gram<<<dim3(8, 8, 8), 256, 0, stream>>>(xh, xl, x2h, x2l, xxv, yyv,
      Cmat, wCt);
  k_sink_reg<<<SNB, 512, 0, stream>>>(Cmat, wCt, db, part, oloss);
}

// Round 14
// 739.310 us; speedup vs baseline: 1.0523x; 1.0523x over previous
//
#include <hip/hip_runtime.h>
#include <math.h>

// Problem constants (fixed by the reference)
#define BN   8
#define NN   1024
#define FIN  256
#define HIDN 128
#define KTOP 513          // int(1024*0.5)+1
#define NITER 20          // opt_epochs in setup_inputs
#define EPS_S 0.01f
#define INV_EPS 100.0f
#define LOG_MU (-6.9314718055994531f)   // -log(1024)
#define SNB 256           // blocks in persistent sinkhorn kernel
#define SENTU 0xFFFFFFFFu

typedef __attribute__((ext_vector_type(8))) short bfrag8;   // 8 bf16 (4 VGPR)
typedef __attribute__((ext_vector_type(4))) float facc4;    // MFMA accumulator

#define GLOAD16(g, l) __builtin_amdgcn_global_load_lds( \
    (const __attribute__((address_space(1))) unsigned int*)(g), \
    (__attribute__((address_space(3))) unsigned int*)(l), 16, 0, 0)

static __device__ __forceinline__ float wred_sum(float s) {
#pragma unroll
  for (int o = 32; o > 0; o >>= 1) s += __shfl_xor(s, o);
  return s;
}
static __device__ __forceinline__ unsigned short f2b(float f) {
  unsigned int u = __float_as_uint(f);
  u += 0x7fff + ((u >> 16) & 1);      // RNE
  return (unsigned short)(u >> 16);
}
static __device__ __forceinline__ float b2f(unsigned short h) {
  return __uint_as_float((unsigned int)h << 16);
}

// ---- rowstats (4 rows/block) from fp32: d, rmask; optional bf16+fp32 copy --
template<int WRBF, int WCOPY>
__global__ __launch_bounds__(256) void k_rowstats4(const float* __restrict__ adj,
                                                   float* __restrict__ dv,
                                                   float* __restrict__ rm,
                                                   unsigned short* __restrict__ abf,
                                                   float* __restrict__ ocopy) {
  int r0 = blockIdx.x << 2;
  int t = threadIdx.x, lane = t & 63, wv = t >> 6;
  __shared__ float sm[4][4];
#pragma unroll
  for (int r = 0; r < 4; ++r) {
    float4 v = ((const float4*)(adj + (long)(r0 + r) * NN))[t];
    if (WRBF) {
      ushort4 h; h.x = f2b(v.x); h.y = f2b(v.y); h.z = f2b(v.z); h.w = f2b(v.w);
      *(ushort4*)(abf + (long)(r0 + r) * NN + t * 4) = h;
    }
    if (WCOPY) ((float4*)(ocopy + (long)(r0 + r) * NN))[t] = v;
    float s = (v.x + v.y) + (v.z + v.w);
    s = wred_sum(s);
    if (lane == 0) sm[wv][r] = s;
  }
  __syncthreads();
  if (t < 4) {
    float tot = sm[0][t] + sm[1][t] + sm[2][t] + sm[3][t];
    dv[r0 + t] = rsqrtf(fmaxf(tot + 1.0f, 1.0f));
    rm[r0 + t] = tot > 0.0f ? 1.0f : 0.0f;
  }
}

// ---- d/rm from fused rowsum buffer -----------------------------------------
__global__ __launch_bounds__(256) void k_dfrom(const float* __restrict__ rs,
                                               float* __restrict__ dv,
                                               float* __restrict__ rm) {
  int i = blockIdx.x * 256 + threadIdx.x;
  float tot = rs[i];
  dv[i] = rsqrtf(fmaxf(tot + 1.0f, 1.0f));
  rm[i] = tot > 0.0f ? 1.0f : 0.0f;
}

// ---------------- fp32 -> bf16 elementwise ----------------------------------
__global__ __launch_bounds__(256) void k_f2b(const float* __restrict__ X,
                                             unsigned short* __restrict__ Y) {
  long i = ((long)blockIdx.x * 256 + threadIdx.x) * 4;
  float4 v = *(const float4*)(X + i);
  Y[i] = f2b(v.x); Y[i + 1] = f2b(v.y); Y[i + 2] = f2b(v.z); Y[i + 3] = f2b(v.w);
}

// ---- W1 [256][128] fp32 -> W1t [128][256] bf16 -----------------------------
__global__ __launch_bounds__(256) void k_w1t(const float* __restrict__ W,
                                             unsigned short* __restrict__ Wt) {
  int idx = blockIdx.x * 256 + threadIdx.x;   // 32768
  int n = idx >> 8, k = idx & 255;
  Wt[idx] = f2b(W[k * HIDN + n]);
}

// ---- fused sqnorm + hi/lo bf16 split for BOTH x and x2 (grid 4096) ---------
__global__ __launch_bounds__(256) void k_prep2(
    const float* __restrict__ X0, const float* __restrict__ X1,
    unsigned short* __restrict__ Xh0, unsigned short* __restrict__ Xl0,
    unsigned short* __restrict__ Xh1, unsigned short* __restrict__ Xl1,
    float* __restrict__ sq0, float* __restrict__ sq1) {
  int bb = blockIdx.x;
  const float* X; unsigned short* Xh; unsigned short* Xl; float* sq; int rb;
  if (bb < 2048) { X = X0; Xh = Xh0; Xl = Xl0; sq = sq0; rb = bb; }
  else { X = X1; Xh = Xh1; Xl = Xl1; sq = sq1; rb = bb - 2048; }
  int t = threadIdx.x, lane = t & 63, wv = t >> 6;
  int row = rb * 4 + wv;
  long base = (long)row * FIN + lane * 4;
  float4 v = *(const float4*)(X + base);
  ushort4 h, l;
  h.x = f2b(v.x); l.x = f2b(v.x - b2f(h.x));
  h.y = f2b(v.y); l.y = f2b(v.y - b2f(h.y));
  h.z = f2b(v.z); l.z = f2b(v.z - b2f(h.z));
  h.w = f2b(v.w); l.w = f2b(v.w - b2f(h.w));
  *(ushort4*)(Xh + base) = h;
  *(ushort4*)(Xl + base) = l;
  float s = v.x * v.x + v.y * v.y + v.z * v.z + v.w * v.w;
  s = wred_sum(s);
  if (lane == 0) sq[row] = s;
}

// ---------------- fp32 [R][C] -> bf16 [C][R] transpose ----------------------
__global__ __launch_bounds__(256) void k_transp(const float* __restrict__ X,
                                                unsigned short* __restrict__ Xt,
                                                int R, int C) {
  __shared__ float tile[64][65];
  long bb = blockIdx.z;
  const float* Xb = X + bb * (long)R * C;
  unsigned short* Xtb = Xt + bb * (long)R * C;
  int r0 = blockIdx.y * 64, c0 = blockIdx.x * 64;
  int t = threadIdx.x;
  int tr = t >> 4, tc4 = (t & 15) * 4;
#pragma unroll
  for (int p = 0; p < 4; ++p) {
    float4 v = *(const float4*)(Xb + (long)(r0 + tr + p * 16) * C + c0 + tc4);
    tile[tr + p * 16][tc4 + 0] = v.x; tile[tr + p * 16][tc4 + 1] = v.y;
    tile[tr + p * 16][tc4 + 2] = v.z; tile[tr + p * 16][tc4 + 3] = v.w;
  }
  __syncthreads();
  int jj = t >> 2, i0 = (t & 3) * 16;
  unsigned short* orow = Xtb + (long)(c0 + jj) * R + r0 + i0;
#pragma unroll
  for (int q = 0; q < 16; ++q) orow[q] = f2b(tile[i0 + q][jj]);
}

// ---- scale-transpose-cast: Bg[b][n][j] = bf16(d[b*1024+j]*XW[b][j][n]) -----
template<int SPLIT>
__global__ __launch_bounds__(256) void k_stc(const float* __restrict__ XW,
                                             const float* __restrict__ dvv,
                                             unsigned short* __restrict__ Bh,
                                             unsigned short* __restrict__ Bl,
                                             int F) {
  __shared__ float tile[64][65];
  __shared__ float dl[64];
  int bz = blockIdx.z;
  const float* Xb = XW + (long)bz * NN * F;
  int j0 = blockIdx.x * 64;   // node dim
  int n0 = blockIdx.y * 64;   // feature dim
  int t = threadIdx.x;
  int tr = t >> 4, tc4 = (t & 15) * 4;
#pragma unroll
  for (int p = 0; p < 4; ++p) {
    float4 v = *(const float4*)(Xb + (long)(j0 + tr + p * 16) * F + n0 + tc4);
    tile[tr + p * 16][tc4 + 0] = v.x; tile[tr + p * 16][tc4 + 1] = v.y;
    tile[tr + p * 16][tc4 + 2] = v.z; tile[tr + p * 16][tc4 + 3] = v.w;
  }
  if (t < 64) dl[t] = dvv[(bz << 10) + j0 + t];
  __syncthreads();
  int nn = t >> 2, i0 = (t & 3) * 16;
  long obase = ((long)bz * F + n0 + nn) * NN + j0 + i0;
#pragma unroll
  for (int q = 0; q < 16; ++q) {
    float v = tile[i0 + q][nn] * dl[i0 + q];
    unsigned short h = f2b(v);
    Bh[obase + q] = h;
    if (SPLIT) Bl[obase + q] = f2b(v - b2f(h));
  }
}

// ---------------- bf16 NT MFMA GEMM: C[m,n] = sum_k A[m,k]*B[n,k] -----------
// WBF: 0 none, 1 bf16, 2 bf16 hi+lo; RS: accumulate fp32 row sums into RSp
template<int WF32, int WBF, int RS>
__global__ __launch_bounds__(256) void k_mfma_nt(
    const unsigned short* __restrict__ A, const unsigned short* __restrict__ B,
    float* __restrict__ Cf, unsigned short* __restrict__ Cb,
    unsigned short* __restrict__ Cb2,
    int K, int ldA, int ldB, int ldC, long sA, long sB, long sC,
    float* __restrict__ RSp) {
  __shared__ unsigned short As[128 * 32];
  __shared__ unsigned short Bs[128 * 32];
  __shared__ float rsum[RS ? 128 : 4];
  int bz = blockIdx.z;
  A += bz * sA; B += bz * sB;
  int m0 = blockIdx.y * 128, n0 = blockIdx.x * 128;
  int tid = threadIdx.x, lane = tid & 63, w = tid >> 6;
  int wr = w >> 1, wc = w & 1;
  facc4 acc[4][4];
#pragma unroll
  for (int i = 0; i < 4; ++i)
#pragma unroll
    for (int j = 0; j < 4; ++j)
#pragma unroll
      for (int q = 0; q < 4; ++q) acc[i][j][q] = 0.f;

  int rA0 = w * 16 + (lane >> 2);
  int kslot = lane & 3;

  for (int k0 = 0; k0 < K; k0 += 32) {
#pragma unroll
    for (int i = 0; i < 2; ++i) {
      int row = i * 64 + rA0;
      int ks = (kslot ^ (row & 3)) << 3;   // pre-swizzled global source
      GLOAD16(A + (long)(m0 + row) * ldA + k0 + ks, As + (i * 64 + w * 16) * 32);
      GLOAD16(B + (long)(n0 + row) * ldB + k0 + ks, Bs + (i * 64 + w * 16) * 32);
    }
    __syncthreads();
    bfrag8 af[4], bfr[4];
#pragma unroll
    for (int mi = 0; mi < 4; ++mi) {
      int row = wr * 64 + mi * 16 + (lane & 15);
      int sl = (((lane >> 4) ^ (row & 3)) << 3);   // swizzled read
      af[mi] = *(const bfrag8*)(As + row * 32 + sl);
    }
#pragma unroll
    for (int ni = 0; ni < 4; ++ni) {
      int row = wc * 64 + ni * 16 + (lane & 15);
      int sl = (((lane >> 4) ^ (row & 3)) << 3);
      bfr[ni] = *(const bfrag8*)(Bs + row * 32 + sl);
    }
#pragma unroll
    for (int mi = 0; mi < 4; ++mi)
#pragma unroll
      for (int ni = 0; ni < 4; ++ni)
        acc[mi][ni] = __builtin_amdgcn_mfma_f32_16x16x32_bf16(
            af[mi], bfr[ni], acc[mi][ni], 0, 0, 0);
    __syncthreads();
  }
  if (RS) {
    if (tid < 128) rsum[tid] = 0.f;
    __syncthreads();
  }
  if (WF32) Cf += bz * sC;
  if (WBF) Cb += bz * sC;
  if (WBF == 2) Cb2 += bz * sC;
#pragma unroll
  for (int mi = 0; mi < 4; ++mi) {
    int rowb = m0 + wr * 64 + mi * 16 + ((lane >> 4) << 2);
#pragma unroll
    for (int q = 0; q < 4; ++q) {
      float rp = 0.f;
#pragma unroll
      for (int ni = 0; ni < 4; ++ni) {
        int col = n0 + wc * 64 + ni * 16 + (lane & 15);
        long off = (long)(rowb + q) * ldC + col;
        float v = acc[mi][ni][q];
        if (WF32) Cf[off] = v;
        if (WBF == 1) Cb[off] = f2b(v);
        if (WBF == 2) {
          unsigned short h = f2b(v);
          Cb[off] = h;
          Cb2[off] = f2b(v - b2f(h));
        }
        if (RS) rp += v;
      }
      if (RS) {
        rp += __shfl_xor(rp, 1); rp += __shfl_xor(rp, 2);
        rp += __shfl_xor(rp, 4); rp += __shfl_xor(rp, 8);
        if ((lane & 15) == 0)
          atomicAdd(&rsum[rowb + q - m0], rp);
      }
    }
  }
  if (RS) {
    __syncthreads();
    if (tid < 128) atomicAdd(&RSp[(long)bz * NN + m0 + tid], rsum[tid]);
  }
}

// ---- merged coarsening GEMM: grid (9, 8, 8) --------------------------------
__global__ __launch_bounds__(256) void k_coars(
    const unsigned short* __restrict__ St, const unsigned short* __restrict__ Badj,
    const unsigned short* __restrict__ cxt,
    unsigned short* __restrict__ tmpo, float* __restrict__ embo) {
  __shared__ unsigned short As[128 * 32];
  __shared__ unsigned short Bs[128 * 32];
  int bz = blockIdx.z;
  int bx = blockIdx.x;
  int em = (bx == 8);
  const unsigned short* A = St + (long)bz * 1048576;
  const unsigned short* B = em ? (cxt + (long)bz * 131072)
                               : (Badj + (long)bz * 1048576);
  int m0 = blockIdx.y * 128, n0 = em ? 0 : bx * 128;
  int tid = threadIdx.x, lane = tid & 63, w = tid >> 6;
  int wr = w >> 1, wc = w & 1;
  facc4 acc[4][4];
#pragma unroll
  for (int i = 0; i < 4; ++i)
#pragma unroll
    for (int j = 0; j < 4; ++j)
#pragma unroll
      for (int q = 0; q < 4; ++q) acc[i][j][q] = 0.f;

  int rA0 = w * 16 + (lane >> 2);
  int kslot = lane & 3;

  for (int k0 = 0; k0 < NN; k0 += 32) {
#pragma unroll
    for (int i = 0; i < 2; ++i) {
      int row = i * 64 + rA0;
      int ks = (kslot ^ (row & 3)) << 3;
      GLOAD16(A + (long)(m0 + row) * NN + k0 + ks, As + (i * 64 + w * 16) * 32);
      GLOAD16(B + (long)(n0 + row) * NN + k0 + ks, Bs + (i * 64 + w * 16) * 32);
    }
    __syncthreads();
    bfrag8 af[4], bfr[4];
#pragma unroll
    for (int mi = 0; mi < 4; ++mi) {
      int row = wr * 64 + mi * 16 + (lane & 15);
      int sl = (((lane >> 4) ^ (row & 3)) << 3);
      af[mi] = *(const bfrag8*)(As + row * 32 + sl);
    }
#pragma unroll
    for (int ni = 0; ni < 4; ++ni) {
      int row = wc * 64 + ni * 16 + (lane & 15);
      int sl = (((lane >> 4) ^ (row & 3)) << 3);
      bfr[ni] = *(const bfrag8*)(Bs + row * 32 + sl);
    }
#pragma unroll
    for (int mi = 0; mi < 4; ++mi)
#pragma unroll
      for (int ni = 0; ni < 4; ++ni)
        acc[mi][ni] = __builtin_amdgcn_mfma_f32_16x16x32_bf16(
            af[mi], bfr[ni], acc[mi][ni], 0, 0, 0);
    __syncthreads();
  }
#pragma unroll
  for (int mi = 0; mi < 4; ++mi) {
    int rowb = m0 + wr * 64 + mi * 16 + ((lane >> 4) << 2);
#pragma unroll
    for (int ni = 0; ni < 4; ++ni) {
      int col = n0 + wc * 64 + ni * 16 + (lane & 15);
#pragma unroll
      for (int q = 0; q < 4; ++q) {
        float v = acc[mi][ni][q];
        if (em)
          embo[(long)bz * 131072 + (long)(rowb + q) * HIDN + col] = v;
        else
          tmpo[(long)bz * 1048576 + (long)(rowb + q) * NN + col] = f2b(v);
      }
    }
  }
}

// ---- GCN MFMA: x = d_m*(sum_k A[m,k]*B[n,k] + d_m*XW[m,n]) + bias[n] -------
template<int SPLIT, int RELU>
__global__ __launch_bounds__(256) void k_mfma_gcn(
    const unsigned short* __restrict__ Ah, const unsigned short* __restrict__ Al,
    const unsigned short* __restrict__ Bh, const unsigned short* __restrict__ Bl,
    const float* __restrict__ dvv, const float* __restrict__ XW,
    const float* __restrict__ bias, float* __restrict__ Cf, int F) {
  __shared__ unsigned short AsH[128 * 32], BsH[128 * 32];
  __shared__ unsigned short AsL[SPLIT ? 128 * 32 : 16], BsL[SPLIT ? 128 * 32 : 16];
  int bz = blockIdx.z;
  const unsigned short* Ahb = Ah + (long)bz * NN * NN;
  const unsigned short* Alb = SPLIT ? Al + (long)bz * NN * NN : nullptr;
  const unsigned short* Bhb = Bh + (long)bz * F * NN;
  const unsigned short* Blb = SPLIT ? Bl + (long)bz * F * NN : nullptr;
  int m0 = blockIdx.y * 128, n0 = blockIdx.x * 128;
  int tid = threadIdx.x, lane = tid & 63, w = tid >> 6;
  int wr = w >> 1, wc = w & 1;
  facc4 acc[4][4];
#pragma unroll
  for (int i = 0; i < 4; ++i)
#pragma unroll
    for (int j = 0; j < 4; ++j)
#pragma unroll
      for (int q = 0; q < 4; ++q) acc[i][j][q] = 0.f;

  int rA0 = w * 16 + (lane >> 2);
  int kslot = lane & 3;

  for (int k0 = 0; k0 < NN; k0 += 32) {
#pragma unroll
    for (int i = 0; i < 2; ++i) {
      int row = i * 64 + rA0;
      int ks = (kslot ^ (row & 3)) << 3;
      int ld = (i * 64 + w * 16) * 32;
      GLOAD16(Ahb + (long)(m0 + row) * NN + k0 + ks, AsH + ld);
      GLOAD16(Bhb + (long)(n0 + row) * NN + k0 + ks, BsH + ld);
      if (SPLIT) {
        GLOAD16(Alb + (long)(m0 + row) * NN + k0 + ks, AsL + ld);
        GLOAD16(Blb + (long)(n0 + row) * NN + k0 + ks, BsL + ld);
      }
    }
    __syncthreads();
    bfrag8 afh[4], bfh[4], afl[4], bfl[4];
#pragma unroll
    for (int mi = 0; mi < 4; ++mi) {
      int row = wr * 64 + mi * 16 + (lane & 15);
      int sl = (((lane >> 4) ^ (row & 3)) << 3);
      afh[mi] = *(const bfrag8*)(AsH + row * 32 + sl);
      if (SPLIT) afl[mi] = *(const bfrag8*)(AsL + row * 32 + sl);
    }
#pragma unroll
    for (int ni = 0; ni < 4; ++ni) {
      int row = wc * 64 + ni * 16 + (lane & 15);
      int sl = (((lane >> 4) ^ (row & 3)) << 3);
      bfh[ni] = *(const bfrag8*)(BsH + row * 32 + sl);
      if (SPLIT) bfl[ni] = *(const bfrag8*)(BsL + row * 32 + sl);
    }
#pragma unroll
    for (int mi = 0; mi < 4; ++mi)
#pragma unroll
      for (int ni = 0; ni < 4; ++ni) {
        acc[mi][ni] = __builtin_amdgcn_mfma_f32_16x16x32_bf16(
            afh[mi], bfh[ni], acc[mi][ni], 0, 0, 0);
        if (SPLIT) {
          acc[mi][ni] = __builtin_amdgcn_mfma_f32_16x16x32_bf16(
              afh[mi], bfl[ni], acc[mi][ni], 0, 0, 0);
          acc[mi][ni] = __builtin_amdgcn_mfma_f32_16x16x32_bf16(
              afl[mi], bfh[ni], acc[mi][ni], 0, 0, 0);
        }
      }
    __syncthreads();
  }
  Cf += (long)bz * NN * F;
#pragma unroll
  for (int mi = 0; mi < 4; ++mi) {
    int rowb = m0 + wr * 64 + mi * 16 + ((lane >> 4) << 2);
#pragma unroll
    for (int ni = 0; ni < 4; ++ni) {
      int col = n0 + wc * 64 + ni * 16 + (lane & 15);
      float bcol = bias[col];
#pragma unroll
      for (int q = 0; q < 4; ++q) {
        float dm = dvv[(bz << 10) + rowb + q];
        float xwv = XW[((long)(bz << 10) + rowb + q) * F + col];
        float v = dm * (acc[mi][ni][q] + dm * xwv) + bcol;
        if (RELU) v = fmaxf(v, 0.f);
        Cf[(long)(rowb + q) * F + col] = v;
      }
    }
  }
}

// ---- split-bf16 3-product NT MFMA Gram + fused C^T write -------------------
__global__ __launch_bounds__(256) void k_mfma_gram(
    const unsigned short* __restrict__ Ah, const unsigned short* __restrict__ Al,
    const unsigned short* __restrict__ Bh, const unsigned short* __restrict__ Bl,
    const float* __restrict__ xx, const float* __restrict__ yy,
    float* __restrict__ Cf, float* __restrict__ Ct) {
  __shared__ unsigned short AsH[128 * 32], AsL[128 * 32];
  __shared__ unsigned short BsH[128 * 32], BsL[128 * 32];
  int bz = blockIdx.z;
  long boff = (long)bz * NN * FIN;
  Ah += boff; Al += boff; Bh += boff; Bl += boff;
  const float* xxb = xx + (bz << 10);
  const float* yyb = yy + (bz << 10);
  int m0 = blockIdx.y * 128, n0 = blockIdx.x * 128;
  int tid = threadIdx.x, lane = tid & 63, w = tid >> 6;
  int wr = w >> 1, wc = w & 1;
  facc4 acc[4][4];
#pragma unroll
  for (int i = 0; i < 4; ++i)
#pragma unroll
    for (int j = 0; j < 4; ++j)
#pragma unroll
      for (int q = 0; q < 4; ++q) acc[i][j][q] = 0.f;

  int rA0 = w * 16 + (lane >> 2);
  int kslot = lane & 3;

  for (int k0 = 0; k0 < FIN; k0 += 32) {
#pragma unroll
    for (int i = 0; i < 2; ++i) {
      int row = i * 64 + rA0;
      int ks = (kslot ^ (row & 3)) << 3;
      long ga = (long)(m0 + row) * FIN + k0 + ks;
      long gb = (long)(n0 + row) * FIN + k0 + ks;
      int ld = (i * 64 + w * 16) * 32;
      GLOAD16(Ah + ga, AsH + ld);
      GLOAD16(Al + ga, AsL + ld);
      GLOAD16(Bh + gb, BsH + ld);
      GLOAD16(Bl + gb, BsL + ld);
    }
    __syncthreads();
    bfrag8 afh[4], afl[4], bfh[4], bfl[4];
#pragma unroll
    for (int mi = 0; mi < 4; ++mi) {
      int row = wr * 64 + mi * 16 + (lane & 15);
      int sl = (((lane >> 4) ^ (row & 3)) << 3);
      afh[mi] = *(const bfrag8*)(AsH + row * 32 + sl);
      afl[mi] = *(const bfrag8*)(AsL + row * 32 + sl);
    }
#pragma unroll
    for (int ni = 0; ni < 4; ++ni) {
      int row = wc * 64 + ni * 16 + (lane & 15);
      int sl = (((lane >> 4) ^ (row & 3)) << 3);
      bfh[ni] = *(const bfrag8*)(BsH + row * 32 + sl);
      bfl[ni] = *(const bfrag8*)(BsL + row * 32 + sl);
    }
#pragma unroll
    for (int mi = 0; mi < 4; ++mi)
#pragma unroll
      for (int ni = 0; ni < 4; ++ni) {
        acc[mi][ni] = __builtin_amdgcn_mfma_f32_16x16x32_bf16(
            afh[mi], bfh[ni], acc[mi][ni], 0, 0, 0);
        acc[mi][ni] = __builtin_amdgcn_mfma_f32_16x16x32_bf16(
            afh[mi], bfl[ni], acc[mi][ni], 0, 0, 0);
        acc[mi][ni] = __builtin_amdgcn_mfma_f32_16x16x32_bf16(
            afl[mi], bfh[ni], acc[mi][ni], 0, 0, 0);
      }
    __syncthreads();
  }
  Cf += (long)bz * NN * NN;
  Ct += (long)bz * NN * NN;
#pragma unroll
  for (int mi = 0; mi < 4; ++mi) {
    int rowb = m0 + wr * 64 + mi * 16 + ((lane >> 4) << 2);
#pragma unroll
    for (int ni = 0; ni < 4; ++ni) {
      int col = n0 + wc * 64 + ni * 16 + (lane & 15);
      float yv = yyb[col];
      float4 tv;
#pragma unroll
      for (int q = 0; q < 4; ++q) {
        float v = xxb[rowb + q] + yv - 2.f * acc[mi][ni][q];
        Cf[(long)(rowb + q) * NN + col] = v;
        ((float*)&tv)[q] = v;
      }
      *(float4*)(Ct + (long)col * NN + rowb) = tv;   // transposed write
    }
  }
}

// ---------------- s0 = cx @ Watt  (per-row dot, HID=128) --------------------
__global__ __launch_bounds__(256) void k_rowdot(const float* __restrict__ X,
                                                const float* __restrict__ w,
                                                float* __restrict__ out) {
  int t = threadIdx.x; int lane = t & 63; int wv = t >> 6;
  int row = blockIdx.x * 4 + wv;
  const float* xr = X + (long)row * HIDN;
  float s = xr[lane] * w[lane] + xr[lane + 64] * w[lane + 64];
  s = wred_sum(s);
  if (lane == 0) out[row] = s;
}

// ---- alpha (4 rows/block) from bf16 adj ------------------------------------
__global__ __launch_bounds__(256) void k_alpha4b(const unsigned short* __restrict__ adj,
                                                 const float* __restrict__ dv,
                                                 const float* __restrict__ s0,
                                                 const float* __restrict__ batt,
                                                 float* __restrict__ alpha) {
  int r0 = blockIdx.x << 2; int b = r0 >> 10; int i0 = r0 & (NN - 1);
  int t = threadIdx.x, lane = t & 63, wv = t >> 6;
  float4 d4 = ((const float4*)(dv + (b << 10)))[t];
  float4 s4 = ((const float4*)(s0 + (b << 10)))[t];
  float w4[4];
  w4[0] = d4.x * s4.x; w4[1] = d4.y * s4.y; w4[2] = d4.z * s4.z; w4[3] = d4.w * s4.w;
  __shared__ float sm[4][4];
#pragma unroll
  for (int r = 0; r < 4; ++r) {
    ushort4 h = ((const ushort4*)(adj + (long)(r0 + r) * NN))[t];
    float dot = b2f(h.x) * w4[0] + b2f(h.y) * w4[1] +
                b2f(h.z) * w4[2] + b2f(h.w) * w4[3];
    int i = i0 + r;
    if ((i >> 2) == t) dot += w4[i & 3];   // +I diagonal
    dot = wred_sum(dot);
    if (lane == 0) sm[wv][r] = dot;
  }
  __syncthreads();
  if (t < 4) {
    float dot = sm[0][t] + sm[1][t] + sm[2][t] + sm[3][t];
    float tt = dv[r0 + t] * dot + batt[0];
    alpha[r0 + t] = 1.f / (1.f + __expf(-tt * tt));
  }
}

// ---- per-batch k-th largest via 8-bit radix select --------------------------
// alpha > 0 so uint ordering == float ordering. Exact (duplicate-correct).
__global__ __launch_bounds__(512) void k_topk(const float* __restrict__ alpha,
                                              float* __restrict__ cut) {
  int b = blockIdx.x, t = threadIdx.x;
  unsigned e0 = __float_as_uint(alpha[(b << 10) + t]);
  unsigned e1 = __float_as_uint(alpha[(b << 10) + t + 512]);
  __shared__ int hist[256];
  __shared__ unsigned pref;
  __shared__ int kk;
  if (t == 0) { pref = 0u; kk = KTOP; }
  __syncthreads();
  for (int pass = 0; pass < 4; ++pass) {
    int shift = 24 - pass * 8;
    if (t < 256) hist[t] = 0;
    __syncthreads();
    unsigned p = pref; int k = kk;
    if (pass == 0 || (e0 >> (shift + 8)) == p)
      atomicAdd(&hist[(e0 >> shift) & 255], 1);
    if (pass == 0 || (e1 >> (shift + 8)) == p)
      atomicAdd(&hist[(e1 >> shift) & 255], 1);
    __syncthreads();
    if (t < 64) {   // single-wave suffix scan over 256 bins (4 bins/lane)
      int h0 = hist[4 * t], h1 = hist[4 * t + 1];
      int h2 = hist[4 * t + 2], h3 = hist[4 * t + 3];
      int s3 = h3, s2 = h2 + s3, s1 = h1 + s2, s0 = h0 + s1;
      int T = s0, tin = T;
#pragma unroll
      for (int off = 1; off < 64; off <<= 1) {
        int v = __shfl_down(tin, off);
        if (t + off < 64) tin += v;
      }
      int above = tin - T;   // sum over lanes > t
      int suf0 = s0 + above, suf1 = s1 + above;
      int suf2 = s2 + above, suf3 = s3 + above, sufN = above;
      if (suf0 >= k && suf1 < k) { pref = (p << 8) | (unsigned)(4 * t + 0); kk = k - suf1; }
      if (suf1 >= k && suf2 < k) { pref = (p << 8) | (unsigned)(4 * t + 1); kk = k - suf2; }
      if (suf2 >= k && suf3 < k) { pref = (p << 8) | (unsigned)(4 * t + 2); kk = k - suf3; }
      if (suf3 >= k && sufN < k) { pref = (p << 8) | (unsigned)(4 * t + 3); kk = k - sufN; }
    }
    __syncthreads();
  }
  if (t == 0) cut[b] = __uint_as_float(pref);
}

// ---- S build (4 rows/block) from bf16 adj ----------------------------------
__global__ __launch_bounds__(256) void k_sbuild4b(const unsigned short* __restrict__ adj,
                                                  const float* __restrict__ dv,
                                                  const float* __restrict__ rm,
                                                  const float* __restrict__ alpha,
                                                  const float* __restrict__ cut,
                                                  float* __restrict__ S) {
  int r0 = blockIdx.x << 2; int b = r0 >> 10; int i0 = r0 & (NN - 1);
  int t = threadIdx.x, lane = t & 63, wv = t >> 6;
  float cb = cut[b];
  float4 d4 = ((const float4*)(dv + (b << 10)))[t];
  float4 al4 = ((const float4*)(alpha + (b << 10)))[t];
  float4 dg;
  dg.x = d4.x * fmaxf(al4.x + 1e-7f - cb, 0.f);
  dg.y = d4.y * fmaxf(al4.y + 1e-7f - cb, 0.f);
  dg.z = d4.z * fmaxf(al4.z + 1e-7f - cb, 0.f);
  dg.w = d4.w * fmaxf(al4.w + 1e-7f - cb, 0.f);
  __shared__ float sm[4][4];
  __shared__ float sinv[4];
  float4 vals[4];
#pragma unroll
  for (int r = 0; r < 4; ++r) {
    float di = dv[r0 + r] * rm[r0 + r];
    ushort4 h = ((const ushort4*)(adj + (long)(r0 + r) * NN))[t];
    float4 a4;
    a4.x = b2f(h.x); a4.y = b2f(h.y); a4.z = b2f(h.z); a4.w = b2f(h.w);
    int i = i0 + r;
    if ((i >> 2) == t) ((float*)&a4)[i & 3] += 1.f;
    vals[r].x = di * dg.x * a4.x; vals[r].y = di * dg.y * a4.y;
    vals[r].z = di * dg.z * a4.z; vals[r].w = di * dg.w * a4.w;
    float s = (fabsf(vals[r].x) + fabsf(vals[r].y)) +
              (fabsf(vals[r].z) + fabsf(vals[r].w));
    s = wred_sum(s);
    if (lane == 0) sm[wv][r] = s;
  }
  __syncthreads();
  if (t < 4) sinv[t] = 1.f / fmaxf(sm[0][t] + sm[1][t] + sm[2][t] + sm[3][t], 1e-12f);
  __syncthreads();
#pragma unroll
  for (int r = 0; r < 4; ++r) {
    float inv = sinv[r];
    float4 o; o.x = vals[r].x * inv; o.y = vals[r].y * inv;
    o.z = vals[r].z * inv; o.w = vals[r].w * inv;
    ((float4*)(S + (long)(r0 + r) * NN))[t] = o;
  }
}

// ---------------- K-split fp32 GEMM (TA=0,TB=0), partials out ---------------
template<int GCN>
__global__ __launch_bounds__(256) void k_gemm_ks(
    const float* __restrict__ A, const float* __restrict__ Bm, float* __restrict__ P,
    int M, int Nn, int K, int KS, long sA, long sB,
    const float* __restrict__ dv) {
  __shared__ float As[8][132];
  __shared__ float Bs[8][132];
  int z = blockIdx.z;
  int b = z / KS, ks = z % KS;
  int KC = K / KS;
  A += (long)b * sA; Bm += (long)b * sB;
  const float* dvb = GCN ? (dv + (long)b * NN) : nullptr;
  int m0 = blockIdx.y * 128, n0 = blockIdx.x * 128;
  int tid = threadIdx.x;
  int tx = tid & 15, ty = tid >> 4;
  float acc[8][8];
#pragma unroll
  for (int i = 0; i < 8; i++)
#pragma unroll
    for (int j = 0; j < 8; j++) acc[i][j] = 0.f;

  float drow = 0.f;
  if (GCN) drow = dvb[m0 + (tid >> 1)];

  for (int k0 = ks * KC; k0 < ks * KC + KC; k0 += 8) {
    {
      int r = tid >> 1, c4 = (tid & 1) * 4;
      float4 av = *(const float4*)(A + (long)(m0 + r) * K + k0 + c4);
      float a4[4] = {av.x, av.y, av.z, av.w};
      if (GCN) {
#pragma unroll
        for (int q = 0; q < 4; ++q) {
          int gj = k0 + c4 + q;
          float val = a4[q] + ((m0 + r) == gj ? 1.f : 0.f);
          a4[q] = drow * dvb[gj] * val;
        }
      }
      As[c4 + 0][r] = a4[0]; As[c4 + 1][r] = a4[1];
      As[c4 + 2][r] = a4[2]; As[c4 + 3][r] = a4[3];
    }
    {
      int kr = tid >> 5, c4 = (tid & 31) * 4;
      float4 bv = *(const float4*)(Bm + (long)(k0 + kr) * Nn + n0 + c4);
      *(float4*)&Bs[kr][c4] = bv;
    }
    __syncthreads();
#pragma unroll
    for (int k = 0; k < 8; ++k) {
      float av[8], bv[8];
      *(float4*)&av[0] = *(const float4*)&As[k][ty * 8];
      *(float4*)&av[4] = *(const float4*)&As[k][ty * 8 + 4];
      *(float4*)&bv[0] = *(const float4*)&Bs[k][tx * 8];
      *(float4*)&bv[4] = *(const float4*)&Bs[k][tx * 8 + 4];
#pragma unroll
      for (int i = 0; i < 8; i++)
#pragma unroll
        for (int j = 0; j < 8; j++)
          acc[i][j] = fmaf(av[i], bv[j], acc[i][j]);
    }
    __syncthreads();
  }
  float* Pz = P + (long)z * M * Nn;
#pragma unroll
  for (int i = 0; i < 8; ++i) {
    int m = m0 + ty * 8 + i;
    float* prow = Pz + (long)m * Nn + n0 + tx * 8;
    *(float4*)&prow[0] = *(float4*)&acc[i][0];
    *(float4*)&prow[4] = *(float4*)&acc[i][4];
  }
}

// ---------------- reduce K-split partials (+bias, +relu) --------------------
template<int RELU, int BIAS>
__global__ __launch_bounds__(256) void k_red_bias(
    const float* __restrict__ P, const float* __restrict__ bias,
    float* __restrict__ out, int Nn, int KS, long chunk) {
  long u = ((long)blockIdx.x * 256 + threadIdx.x) * 4;
  long b = u / chunk; long rem = u % chunk;
  const float* p = P + b * KS * chunk + rem;
  float4 s = *(const float4*)p;
  for (int k = 1; k < KS; ++k) {
    float4 q = *(const float4*)(p + (long)k * chunk);
    s.x += q.x; s.y += q.y; s.z += q.z; s.w += q.w;
  }
  if (BIAS) {
    int n = (int)(rem % Nn);
    s.x += bias[n]; s.y += bias[n + 1]; s.z += bias[n + 2]; s.w += bias[n + 3];
  }
  if (RELU) {
    s.x = fmaxf(s.x, 0.f); s.y = fmaxf(s.y, 0.f);
    s.z = fmaxf(s.z, 0.f); s.w = fmaxf(s.w, 0.f);
  }
  *(float4*)(out + u) = s;
}

// ---------------- column mean over nodes ------------------------------------
__global__ __launch_bounds__(256) void k_colmean(const float* __restrict__ X, int Fd,
                                                 float* __restrict__ out) {
  int nb = Fd >> 6;
  int b = blockIdx.x / nb; int f0 = (blockIdx.x % nb) << 6;
  int t = threadIdx.x;
  int f = f0 + (t & 63); int rc = t >> 6;
  const float* xb = X + (long)b * NN * Fd;
  float s = 0.f;
  for (int i = rc * 256; i < rc * 256 + 256; ++i) s += xb[(long)i * Fd + f];
  __shared__ float sm[256];
  sm[t] = s; __syncthreads();
  if (t < 64) out[b * Fd + f] = (sm[t] + sm[t + 64] + sm[t + 128] + sm[t + 192]) * (1.f / NN);
}

// ======================= persistent register-resident Sinkhorn ==============
// Sentinel barrier (data IS the flag). Dual stores publish EAGERLY (vmcnt(0)
// after store — round-13 showed fire-and-forget delays visibility and costs
// ~35us). LLC (sc0 sc1) coherence. Defer-max with self-correcting refresh.

static __device__ __forceinline__ float2 load_cohere2(const float* p) {
  float2 v;
  asm volatile("global_load_dwordx2 %0, %1, off sc0 sc1\n\ts_waitcnt vmcnt(0)"
               : "=v"(v) : "v"(p) : "memory");
  return v;
}
static __device__ __forceinline__ float load_cohere1(const float* p) {
  float v;
  asm volatile("global_load_dword %0, %1, off sc0 sc1\n\ts_waitcnt vmcnt(0)"
               : "=v"(v) : "v"(p) : "memory");
  return v;
}
static __device__ __forceinline__ void store_cohere1(float* p, float v) {
  asm volatile("global_store_dword %0, %1, off sc0 sc1\n\ts_waitcnt vmcnt(0)"
               :: "v"(p), "v"(v) : "memory");
}

// Poll db[g] slice (2 floats/thread) until non-sentinel, then stage into LDS.
static __device__ __forceinline__ void pollstage(const float* __restrict__ src,
                                                 float* __restrict__ vls, int t) {
  float2 v; int spin = 0;
  for (;;) {
    v = load_cohere2(src + t * 2);
    if ((__float_as_uint(v.x) != SENTU) & (__float_as_uint(v.y) != SENTU)) break;
    if (++spin > (1 << 20)) break;
    __builtin_amdgcn_s_sleep(1);
  }
  __syncthreads();                  // all waves done reading old vls
  *(float2*)(vls + t * 2) = v;
  __syncthreads();
}

// One LSE half-pass for this lane's interleaved row slice.
template<int LOSS, int STORE>
static __device__ __forceinline__ void pass_reg(const float4 (&Cr)[16],
    const float* __restrict__ vls, float* __restrict__ dbout,
    int jc, int row, float* __restrict__ lossacc, float& mxs, int fresh) {
  float4 vr[16];
#pragma unroll
  for (int k = 0; k < 16; ++k)
    vr[k] = *(const float4*)(vls + (k * 16 + jc) * 4);
  float mx = mxs;
  if (fresh) {
    float m0 = -3.0e38f, m1 = m0, m2 = m0, m3 = m0;
#pragma unroll
    for (int k = 0; k < 16; ++k) {
      m0 = fmaxf(m0, vr[k].x - Cr[k].x);
      m1 = fmaxf(m1, vr[k].y - Cr[k].y);
      m2 = fmaxf(m2, vr[k].z - Cr[k].z);
      m3 = fmaxf(m3, vr[k].w - Cr[k].w);
    }
    mx = fmaxf(fmaxf(m0, m1), fmaxf(m2, m3));
#pragma unroll
    for (int m = 1; m <= 8; m <<= 1) mx = fmaxf(mx, __shfl_xor(mx, m));
  }
  float ls, ld = 0.f;
  {
    float s0 = 0, s1 = 0, s2 = 0, s3 = 0, d0 = 0, d1 = 0, d2 = 0, d3 = 0;
#pragma unroll
    for (int k = 0; k < 16; ++k) {
      float e0 = __expf(vr[k].x - Cr[k].x - mx);
      float e1 = __expf(vr[k].y - Cr[k].y - mx);
      float e2 = __expf(vr[k].z - Cr[k].z - mx);
      float e3 = __expf(vr[k].w - Cr[k].w - mx);
      s0 += e0; s1 += e1; s2 += e2; s3 += e3;
      if (LOSS) {
        d0 = fmaf(e0, Cr[k].x, d0); d1 = fmaf(e1, Cr[k].y, d1);
        d2 = fmaf(e2, Cr[k].z, d2); d3 = fmaf(e3, Cr[k].w, d3);
      }
    }
    ls = (s0 + s1) + (s2 + s3);
    if (LOSS) ld = (d0 + d1) + (d2 + d3);
  }
#pragma unroll
  for (int m = 1; m <= 8; m <<= 1) {
    ls += __shfl_xor(ls, m);
    if (LOSS) ld += __shfl_xor(ld, m);
  }
  if (!(ls > 1e-25f && ls < 1e25f)) {       // stale max -> refresh + redo
    float m0 = -3.0e38f, m1 = m0, m2 = m0, m3 = m0;
#pragma unroll
    for (int k = 0; k < 16; ++k) {
      m0 = fmaxf(m0, vr[k].x - Cr[k].x);
      m1 = fmaxf(m1, vr[k].y - Cr[k].y);
      m2 = fmaxf(m2, vr[k].z - Cr[k].z);
      m3 = fmaxf(m3, vr[k].w - Cr[k].w);
    }
    mx = fmaxf(fmaxf(m0, m1), fmaxf(m2, m3));
#pragma unroll
    for (int m = 1; m <= 8; m <<= 1) mx = fmaxf(mx, __shfl_xor(mx, m));
    float s0 = 0, s1 = 0, s2 = 0, s3 = 0, d0 = 0, d1 = 0, d2 = 0, d3 = 0;
#pragma unroll
    for (int k = 0; k < 16; ++k) {
      float e0 = __expf(vr[k].x - Cr[k].x - mx);
      float e1 = __expf(vr[k].y - Cr[k].y - mx);
      float e2 = __expf(vr[k].z - Cr[k].z - mx);
      float e3 = __expf(vr[k].w - Cr[k].w - mx);
      s0 += e0; s1 += e1; s2 += e2; s3 += e3;
      if (LOSS) {
        d0 = fmaf(e0, Cr[k].x, d0); d1 = fmaf(e1, Cr[k].y, d1);
        d2 = fmaf(e2, Cr[k].z, d2); d3 = fmaf(e3, Cr[k].w, d3);
      }
    }
    ls = (s0 + s1) + (s2 + s3);
    if (LOSS) ld = (d0 + d1) + (d2 + d3);
#pragma unroll
    for (int m = 1; m <= 8; m <<= 1) {
      ls += __shfl_xor(ls, m);
      if (LOSS) ld += __shfl_xor(ld, m);
    }
  }
  mxs = mx;
  if (jc == 0) {
    float uval = LOG_MU - (mx + __logf(ls));   // scaled dual u/eps
    if (STORE) store_cohere1(dbout + row, uval);
    if (LOSS) *lossacc += (ld / ls) * (1.0f / 1024.0f);
  }
}

__global__ __launch_bounds__(512, 1) void k_sink_reg(
    const float* __restrict__ Cm, const float* __restrict__ Ct,
    float* __restrict__ db, float* __restrict__ part,
    float* __restrict__ oloss) {
  int bid = blockIdx.x, t = threadIdx.x, lane = t & 63, wvi = t >> 6;
  int jc = lane & 15;
  int grp = bid & 7;          // batch index
  int inner = bid >> 3;       // 0..31
  int row = (grp << 10) + inner * 32 + wvi * 4 + (lane >> 4);
  __shared__ float vls[1024];
  float4 Creg[16], Ctreg[16];
  {
    const float4* cp = (const float4*)(Cm + (long)row * NN);
    const float4* tp = (const float4*)(Ct + (long)row * NN);
#pragma unroll
    for (int k = 0; k < 16; ++k) {
      float4 c = cp[k * 16 + jc], ct = tp[k * 16 + jc];
      Creg[k].x = c.x * INV_EPS;  Creg[k].y = c.y * INV_EPS;
      Creg[k].z = c.z * INV_EPS;  Creg[k].w = c.w * INV_EPS;
      Ctreg[k].x = ct.x * INV_EPS; Ctreg[k].y = ct.y * INV_EPS;
      Ctreg[k].z = ct.z * INV_EPS; Ctreg[k].w = ct.w * INV_EPS;
    }
  }
  // stage db[0] (initial v = zeros) into LDS
  {
    float2 v = *(const float2*)(db + (grp << 10) + t * 2);
    *(float2*)(vls + t * 2) = v;
  }
  __syncthreads();
  float lossacc = 0.f;
  float mxu = 0.f, mxv = 0.f;
  int g = 1;
  for (int it = 0; it < NITER; ++it) {
    pass_reg<0, 1>(Creg, vls, db + (long)g * 8192, jc, row, nullptr, mxu, it == 0);
    pollstage(db + (long)g * 8192 + (grp << 10), vls, t);
    ++g;
    if (it < NITER - 1) {
      pass_reg<0, 1>(Ctreg, vls, db + (long)g * 8192, jc, row, nullptr, mxv, it == 0);
      pollstage(db + (long)g * 8192 + (grp << 10), vls, t);
      ++g;
    } else {
      pass_reg<1, 0>(Ctreg, vls, nullptr, jc, row, &lossacc, mxv, 0);
    }
  }
  // per-block loss partial (data-sentinel handoff)
  float s = wred_sum(lossacc);
  __shared__ float lsm[8];
  if (lane == 0) lsm[wvi] = s;
  __syncthreads();
  if (t == 0) {
    float ps = 0.f;
#pragma unroll
    for (int i = 0; i < 8; ++i) ps += lsm[i];
    store_cohere1(part + bid, ps);
  }
  if (bid == 0) {
    float s2 = 0.f;
    if (t < SNB) {
      int spin = 0;
      for (;;) {
        s2 = load_cohere1(part + t);
        if (__float_as_uint(s2) != SENTU) break;
        if (++spin > (1 << 20)) { s2 = 0.f; break; }
        __builtin_amdgcn_s_sleep(1);
      }
    }
    s2 = wred_sum(s2);
    __shared__ float sm2[8];
    if (lane == 0) sm2[wvi] = s2;
    __syncthreads();
    if (t == 0) {
      float tot = 0.f;
#pragma unroll
      for (int i = 0; i < 8; ++i) tot += sm2[i];
      oloss[0] = tot * EPS_S;   // undo the 1/eps scaling of C' in ld
    }
  }
}

extern "C" void kernel_launch(void* const* d_in, const int* in_sizes, int n_in,
                              void* d_out, int out_size, void* d_ws, size_t ws_size,
                              hipStream_t stream) {
  const float* x    = (const float*)d_in[0];
  const float* adj  = (const float*)d_in[1];
  const float* W1   = (const float*)d_in[3];
  const float* b1   = (const float*)d_in[4];
  const float* Watt = (const float*)d_in[5];
  const float* batt = (const float*)d_in[6];
  const float* W2   = (const float*)d_in[7];
  const float* b2   = (const float*)d_in[8];

  float* out = (float*)d_out;
  float* xs0   = out;                    // [8,128]
  float* xs1   = out + 1024;             // [8,256]
  float* oadj0 = out + 3072;             // [8,1024,1024]
  float* oadj1 = oadj0 + 8388608;
  float* oadj2 = oadj1 + 8388608;        // adj_bf scratch until adj2 written
  float* oS0   = oadj2 + 8388608;
  float* oS1   = oS0 + 8388608;
  float* oloss = oS1 + 8388608;          // [1]

  float* ws   = (float*)d_ws;
  float* wXW  = ws;                       // 2,097,152 (XW1 then XW2)
  float* wCXA = wXW + 2097152;            // 1,048,576 (x1, later emb2)
  float* wCXB = wCXA + 1048576;           // 1,048,576 (emb1)
  float* wR   = wCXB + 1048576;           // 8,388,608 (tmp_bf | P | Cmat)
  float* wX2  = wR + 8388608;             // 2,097,152 (x2)
  float* wStf = wX2 + 2097152;            // 4,194,304 (x_bf/St/Bg2/x-splits)
  float* wCxtf= wStf + 4194304;           // 524,288   (Bg1 / cxt)
  float* wCt  = wCxtf + 524288;           // 8,388,608 (a2h+a2l, then C^T)
  float* smb  = wCt + 8388608;

  unsigned short* tmp_bf = (unsigned short*)wR;                 // 16.7MB half
  unsigned short* a2h    = (unsigned short*)wCt;                // 8,388,608 sh
  unsigned short* a2l    = a2h + 8388608;                       // 8,388,608 sh
  unsigned short* adj_bf = (unsigned short*)oadj2;
  unsigned short* St     = (unsigned short*)wStf;
  unsigned short* cxt    = (unsigned short*)wCxtf;
  unsigned short* x_bf   = (unsigned short*)wStf;               // pre-coarsen
  unsigned short* Bg1    = (unsigned short*)wCxtf;
  unsigned short* Bg2h   = (unsigned short*)wStf;               // post-adj2
  unsigned short* Bg2l   = (unsigned short*)(wStf + 2097152);
  unsigned short* xh  = (unsigned short*)wStf;                  // sinkhorn phase
  unsigned short* xl  = xh + 2097152;
  unsigned short* x2h = xh + 4194304;
  unsigned short* x2l = xh + 6291456;
  float* Cmat = wR;
  float* d0 = smb;            float* rm0 = smb + 8192;
  float* d1 = smb + 16384;    float* rm1 = smb + 24576;
  float* d2 = smb + 32768;    float* rm2 = smb + 40960;
  float* s0v = smb + 49152;   float* alp = smb + 57344;
  float* xxv = smb + 65536;   float* yyv = smb + 73728;
  float* cutv = smb + 98304;  float* part = smb + 98368;  // 256
  unsigned short* W1t = (unsigned short*)(smb + 98624);    // 32768 shorts
  float* db = smb + 131072;    // 41*8192 floats: dual generations
  float* rowsum1 = smb + 131072 + 41 * 8192;               // 8192
  float* rowsum2 = rowsum1 + 8192;                         // 8192

  // ---- sentinel/init memsets first (off critical path) ----
  hipMemsetAsync(db, 0, (size_t)8192 * 4, stream);                 // db[0]=v0=0
  hipMemsetAsync(db + 8192, 0xFF, (size_t)40 * 8192 * 4, stream);  // sentinels
  hipMemsetAsync(part, 0xFF, (size_t)256 * 4, stream);             // sentinels
  hipMemsetAsync(rowsum1, 0, (size_t)16384 * 4, stream);           // both rowsums

  // rowstats on adj + fused bf16 copy (into oadj2 region) + fp32 copy (oadj0)
  k_rowstats4<1, 1><<<2048, 256, 0, stream>>>(adj, d0, rm0, adj_bf, oadj0);

  // ---- GCN1 (MFMA): x1 = relu(d*(adj_bf @ (d.*XW1) + d*XW1_diag) + b1) ----
  k_f2b<<<2048, 256, 0, stream>>>(x, x_bf);
  k_w1t<<<128, 256, 0, stream>>>(W1, W1t);
  k_mfma_nt<1, 0, 0><<<dim3(1, 64, 1), 256, 0, stream>>>(x_bf, W1t, wXW, nullptr,
      nullptr, 256, 256, 256, 128, 0L, 0L, 0L, nullptr);
  k_stc<0><<<dim3(16, 2, 8), 256, 0, stream>>>(wXW, d0, Bg1, nullptr, HIDN);
  k_mfma_gcn<0, 1><<<dim3(1, 8, 8), 256, 0, stream>>>(adj_bf, nullptr, Bg1,
      nullptr, d0, wXW, b1, wCXA, HIDN);
  k_colmean<<<16, 256, 0, stream>>>(wCXA, HIDN, xs0);

  // ---- coarsen layer 1 (bf16 adj reads) ----
  k_rowdot<<<2048, 256, 0, stream>>>(wCXA, Watt, s0v);
  k_alpha4b<<<2048, 256, 0, stream>>>(adj_bf, d0, s0v, batt, alp);
  k_topk<<<8, 512, 0, stream>>>(alp, cutv);
  k_sbuild4b<<<2048, 256, 0, stream>>>(adj_bf, d0, rm0, alp, cutv, oS0);
  k_transp<<<dim3(16, 16, 8), 256, 0, stream>>>(oS0, St, 1024, 1024);
  k_transp<<<dim3(2, 16, 8), 256, 0, stream>>>(wCXA, cxt, 1024, 128);
  k_coars<<<dim3(9, 8, 8), 256, 0, stream>>>(St, adj_bf, cxt, tmp_bf, wCXB);
  // adj1 GEMM with fused rowsum accumulation
  k_mfma_nt<1, 1, 1><<<dim3(8, 8, 8), 256, 0, stream>>>(tmp_bf, St, oadj1, adj_bf,
      nullptr, 1024, 1024, 1024, 1024, 1048576L, 1048576L, 1048576L, rowsum1);
  k_dfrom<<<32, 256, 0, stream>>>(rowsum1, d1, rm1);

  // ---- coarsen layer 2 (bf16 adj1 reads) ----
  k_rowdot<<<2048, 256, 0, stream>>>(wCXB, Watt, s0v);
  k_alpha4b<<<2048, 256, 0, stream>>>(adj_bf, d1, s0v, batt, alp);
  k_topk<<<8, 512, 0, stream>>>(alp, cutv);
  k_sbuild4b<<<2048, 256, 0, stream>>>(adj_bf, d1, rm1, alp, cutv, oS1);
  k_transp<<<dim3(16, 16, 8), 256, 0, stream>>>(oS1, St, 1024, 1024);
  k_transp<<<dim3(2, 16, 8), 256, 0, stream>>>(wCXB, cxt, 1024, 128);
  k_coars<<<dim3(9, 8, 8), 256, 0, stream>>>(St, adj_bf, cxt, tmp_bf, wCXA);
  // adj2 GEMM with fused rowsum accumulation
  k_mfma_nt<1, 2, 1><<<dim3(8, 8, 8), 256, 0, stream>>>(tmp_bf, St, oadj2, a2h,
      a2l, 1024, 1024, 1024, 1024, 1048576L, 1048576L, 1048576L, rowsum2);
  k_dfrom<<<32, 256, 0, stream>>>(rowsum2, d2, rm2);

  // ---- final GCN (split-bf16 MFMA): x2 = d*(A2@(d.*XW2) + d*XW2_diag) + b2 --
  k_gemm_ks<0><<<dim3(2, 64, 2), 256, 0, stream>>>(wCXA, W2, wR, 8192, FIN, HIDN,
      2, 0L, 0L, nullptr);   // P partials in wR first half (tmp_bf dead)
  k_red_bias<0, 0><<<2048, 256, 0, stream>>>(wR, nullptr, wXW, FIN, 2, 2097152L);
  k_stc<1><<<dim3(16, 4, 8), 256, 0, stream>>>(wXW, d2, Bg2h, Bg2l, FIN);
  k_mfma_gcn<1, 0><<<dim3(2, 8, 8), 256, 0, stream>>>(a2h, a2l, Bg2h, Bg2l,
      d2, wXW, b2, wX2, FIN);
  k_colmean<<<32, 256, 0, stream>>>(wX2, FIN, xs1);

  // ---- Sinkhorn: C via split-bf16 MFMA Gram (+fused C^T), reg-resident solve
  k_prep2<<<4096, 256, 0, stream>>>(x, wX2, xh, xl, x2h, x2l, xxv, yyv);
  k_mfma_gram<<<dim3(8, 8, 8), 256, 0, stream>>>(xh, xl, x2h, x2l, xxv, yyv,
      Cmat, wCt);
  k_sink_reg<<<SNB, 512, 0, stream>>>(Cmat, wCt, db, part, oloss);
}